// Round 6
// baseline (365.817 us; speedup 1.0000x reference)
//
#include <hip/hip_runtime.h>
#include <hip/hip_bf16.h>

#define Bv 2
#define Tv 2048
#define Cv 1024
#define Hv 16
#define HSv 64
#define HIDv 2730
#define HIDP 2816
#define Mv 4096

using bf16x8 = __attribute__((ext_vector_type(8))) __bf16;
using f32x4  = __attribute__((ext_vector_type(4))) float;
typedef unsigned long long ull;

__device__ __forceinline__ void gload_lds16(const void* g, void* l) {
    auto gp = (const __attribute__((address_space(1))) unsigned int*)(unsigned long long)(uintptr_t)g;
    auto lp = (__attribute__((address_space(3))) unsigned int*)(unsigned int)(uintptr_t)l;
    __builtin_amdgcn_global_load_lds(gp, lp, 16, 0, 0);
}

// ---------------- fused weight cast ----------------
struct CastSeg { const float* s; __bf16* d; long nsrc; long ntot; int sc; int dc; };
struct CastArgs { CastSeg seg[7]; };

__global__ __launch_bounds__(256) void k_castall(CastArgs a) {
    long gid = (long)blockIdx.x * 256 + threadIdx.x;
    long gstr = (long)gridDim.x * 256;
#pragma unroll 1
    for (int g = 0; g < 7; ++g) {
        CastSeg sg = a.seg[g];
        if (sg.sc == 0) {
            long n4 = sg.ntot >> 2;
            for (long i = gid; i < n4; i += gstr) {
                long base = i * 4;
                float4 v = {0.f, 0.f, 0.f, 0.f};
                if (base < sg.nsrc) v = *(const float4*)(sg.s + base);
                __bf16 o[4] = {(__bf16)v.x, (__bf16)v.y, (__bf16)v.z, (__bf16)v.w};
                *(ull*)(sg.d + base) = *(ull*)o;
            }
        } else {
            for (long i = gid; i < sg.ntot; i += gstr) {
                int r = (int)(i / sg.dc), c = (int)(i % sg.dc);
                sg.d[i] = (c < sg.sc) ? (__bf16)sg.s[(long)r * sg.sc + c] : (__bf16)0.0f;
            }
        }
    }
}

// ---------------- rmsnorm ----------------
__global__ __launch_bounds__(256) void k_rmsnorm(const float* __restrict__ x,
                                                 const float* __restrict__ w,
                                                 float* __restrict__ yf,
                                                 __bf16* __restrict__ yh) {
    int row = blockIdx.x;
    const float4* xr = (const float4*)(x + (size_t)row * Cv);
    float4 a = xr[threadIdx.x];
    float ss = a.x * a.x + a.y * a.y + a.z * a.z + a.w * a.w;
#pragma unroll
    for (int m = 1; m < 64; m <<= 1) ss += __shfl_xor(ss, m);
    __shared__ float red[4];
    if ((threadIdx.x & 63) == 0) red[threadIdx.x >> 6] = ss;
    __syncthreads();
    float tot = red[0] + red[1] + red[2] + red[3];
    float sc = rsqrtf(tot * (1.0f / Cv) + 1e-6f);
    float4 wv = ((const float4*)w)[threadIdx.x];
    float4 o;
    o.x = a.x * sc * wv.x; o.y = a.y * sc * wv.y;
    o.z = a.z * sc * wv.z; o.w = a.w * sc * wv.w;
    ((float4*)(yf + (size_t)row * Cv))[threadIdx.x] = o;
    __bf16* yp = yh + (size_t)row * Cv + threadIdx.x * 4;
    yp[0] = (__bf16)o.x; yp[1] = (__bf16)o.y; yp[2] = (__bf16)o.z; yp[3] = (__bf16)o.w;
}

// ---------------- RoPE: Q in place; K -> KR[bh][t][64] pre-swizzled ----------------
__global__ void k_rope(__bf16* __restrict__ Q, const __bf16* __restrict__ Kin,
                       __bf16* __restrict__ KR,
                       const float* __restrict__ cosT, const float* __restrict__ sinT) {
    long total = (long)Mv * 512;
    long i = (long)blockIdx.x * blockDim.x + threadIdx.x;
    if (i >= total) return;
    int row = (int)(i >> 9);
    int p = (int)(i & 511);
    int h = p >> 5, ii = p & 31;
    int t = row & (Tv - 1), b = row >> 11;
    float c = cosT[t * 32 + ii], s = sinT[t * 32 + ii];
    long idx = (long)row * Cv + h * 64 + 2 * ii;
    float x0 = (float)Q[idx], x1 = (float)Q[idx + 1];
    Q[idx]     = (__bf16)(x0 * c - x1 * s);
    Q[idx + 1] = (__bf16)(x0 * s + x1 * c);
    float y0 = (float)Kin[idx], y1 = (float)Kin[idx + 1];
    __bf16 k0 = (__bf16)(y0 * c - y1 * s);
    __bf16 k1 = (__bf16)(y0 * s + y1 * c);
    int bh = b * 16 + h;
    int colb = (4 * ii) ^ ((t & 7) << 4);
    __bf16 pk[2] = {k0, k1};
    *(unsigned int*)((char*)(KR + ((long)bh * Tv + t) * 64) + colb) = *(unsigned int*)pk;
}

// ---------------- V transpose: VT[bh][f][t], pre-swizzled per 64-key tile ----------------
__global__ __launch_bounds__(256) void k_vtrans(const __bf16* __restrict__ V,
                                                __bf16* __restrict__ VT) {
    __shared__ __bf16 Ts[64][72];
    int t0 = blockIdx.x * 64;
    int bh = blockIdx.y, b = bh >> 4, h = bh & 15;
    const long base = ((long)b * Tv) * Cv + h * 64;
    int tid = threadIdx.x;
    int rr = tid >> 3, cc = (tid & 7) * 8;
#pragma unroll
    for (int it = 0; it < 2; ++it) {
        int row = it * 32 + rr;
        *(int4*)&Ts[row][cc] = *(const int4*)(V + base + (long)(t0 + row) * Cv + cc);
    }
    __syncthreads();
#pragma unroll
    for (int it = 0; it < 2; ++it) {
        int f = it * 32 + rr;
        int tcol = cc ^ ((f & 7) << 3);
        __bf16 tmp[8];
#pragma unroll
        for (int j = 0; j < 8; ++j) tmp[j] = Ts[tcol + j][f];
        *(int4*)(VT + ((long)bh * 64 + f) * Tv + t0 + cc) = *(int4*)tmp;
    }
}

// ---------------- old GEMM (kept for Wo, w3): C = A @ B^T ----------------
template <int BM, int EPI>
__global__ __launch_bounds__(256) void k_gemm(
    const __bf16* __restrict__ A, const __bf16* __restrict__ Bm,
    int M, int N, int K,
    float* __restrict__ outF,
    const float* __restrict__ bias,
    const float* __restrict__ resid) {
    constexpr int NN = (BM == 128) ? 4 : 2;
    __shared__ __align__(16) __bf16 As[BM][64];
    __shared__ __align__(16) __bf16 Bs[128][64];
    int tid = threadIdx.x, lane = tid & 63, wave = tid >> 6;
    int m0 = blockIdx.y * BM, n0 = blockIdx.x * 128;
    int wro = (BM == 128) ? (wave >> 1) * 64 : 0;
    int wco = (BM == 128) ? (wave & 1) * 64 : wave * 32;
    int fr = lane & 15, fo = (lane >> 4) * 8;
    int lr = lane >> 3, lc = (lane & 7) * 8;
    f32x4 acc[4][NN] = {};
    for (int k0 = 0; k0 < K; k0 += 64) {
        __syncthreads();
        int arow0 = wave * (BM / 4);
#pragma unroll
        for (int i = 0; i < BM / 32; ++i) {
            int r = arow0 + i * 8 + lr;
            gload_lds16(A + (long)(m0 + r) * K + k0 + lc, &As[r][lc]);
        }
        int brow0 = wave * 32;
#pragma unroll
        for (int i = 0; i < 4; ++i) {
            int r = brow0 + i * 8 + lr;
            gload_lds16(Bm + (long)(n0 + r) * K + k0 + lc, &Bs[r][lc]);
        }
        __syncthreads();
#pragma unroll
        for (int s = 0; s < 2; ++s) {
            bf16x8 af[4], bf[NN];
#pragma unroll
            for (int m = 0; m < 4; ++m)
                af[m] = *(const bf16x8*)(&As[wro + m * 16 + fr][s * 32 + fo]);
#pragma unroll
            for (int n = 0; n < NN; ++n)
                bf[n] = *(const bf16x8*)(&Bs[wco + n * 16 + fr][s * 32 + fo]);
#pragma unroll
            for (int m = 0; m < 4; ++m)
#pragma unroll
                for (int n = 0; n < NN; ++n)
                    acc[m][n] = __builtin_amdgcn_mfma_f32_16x16x32_bf16(af[m], bf[n], acc[m][n], 0, 0, 0);
        }
    }
    int fq = (lane >> 4) * 4;
#pragma unroll
    for (int m = 0; m < 4; ++m)
#pragma unroll
        for (int n = 0; n < NN; ++n) {
            int row = m0 + wro + m * 16 + fq;
            int col = n0 + wco + n * 16 + fr;
#pragma unroll
            for (int r = 0; r < 4; ++r) {
                float v = acc[m][n][r];
                long idx = (long)(row + r) * N + col;
                if (bias) v += bias[col];
                if (resid) v += resid[idx];
                outF[idx] = v;
            }
        }
}

// ---------------- NEW pipelined GEMM: 128x256 tile, triple-buffer, counted vmcnt ----------------
// EPI 0: outH bf16 [M][N] ; EPI 4: route cols to q/k/v
template <int EPI>
__global__ __launch_bounds__(512, 2) void k_gemm3(
    const __bf16* __restrict__ A, const __bf16* __restrict__ Bm,
    int M, int N, int K,
    __bf16* __restrict__ outH,
    __bf16* __restrict__ qOut, __bf16* __restrict__ kOut, __bf16* __restrict__ vOut) {
    __shared__ __align__(16) __bf16 As[3][128][64];   // 48 KB
    __shared__ __align__(16) __bf16 Bs[3][256][64];   // 96 KB
    int tid = threadIdx.x, lane = tid & 63, wave = tid >> 6;
    int m0 = blockIdx.y * 128, n0 = blockIdx.x * 256;
    int wro = (wave >> 2) * 64, wco = (wave & 3) * 64;
    int fr = lane & 15, g = lane >> 4;
    int sr = tid >> 3, sc = (tid & 7) * 8;            // staging row/col (512 thr)
    int nt = K >> 6;
    f32x4 acc[4][4] = {};

    auto stage = [&](int t, int buf) {
        int k0 = t << 6;
#pragma unroll
        for (int b = 0; b < 2; ++b) {
            int r = b * 64 + sr;
            gload_lds16(A + (long)(m0 + r) * K + k0 + (sc ^ ((r & 7) << 3)), &As[buf][r][sc]);
        }
#pragma unroll
        for (int b = 0; b < 4; ++b) {
            int r = b * 64 + sr;
            gload_lds16(Bm + (long)(n0 + r) * K + k0 + (sc ^ ((r & 7) << 3)), &Bs[buf][r][sc]);
        }
    };

    stage(0, 0);
    stage(1, 1);
    asm volatile("s_waitcnt vmcnt(6)" ::: "memory");  // tile0's 6 loads landed
    __builtin_amdgcn_s_barrier();
    __builtin_amdgcn_sched_barrier(0);

    int bc = 0, bnext = 2;
    for (int t = 0; t < nt; ++t) {
        if (t + 2 < nt) stage(t + 2, bnext);
        __builtin_amdgcn_s_setprio(1);
#pragma unroll
        for (int kk = 0; kk < 2; ++kk) {
            bf16x8 af[4], bfr[4];
#pragma unroll
            for (int m = 0; m < 4; ++m) {
                int r = wro + m * 16 + fr;
                af[m] = *(const bf16x8*)((const char*)&As[bc][r][0] + ((kk * 64 + g * 16) ^ ((r & 7) << 4)));
            }
#pragma unroll
            for (int n = 0; n < 4; ++n) {
                int r = wco + n * 16 + fr;
                bfr[n] = *(const bf16x8*)((const char*)&Bs[bc][r][0] + ((kk * 64 + g * 16) ^ ((r & 7) << 4)));
            }
#pragma unroll
            for (int m = 0; m < 4; ++m)
#pragma unroll
                for (int n = 0; n < 4; ++n)
                    acc[m][n] = __builtin_amdgcn_mfma_f32_16x16x32_bf16(af[m], bfr[n], acc[m][n], 0, 0, 0);
        }
        __builtin_amdgcn_s_setprio(0);
        if (t + 1 < nt) {
            if (t + 2 < nt) asm volatile("s_waitcnt vmcnt(6)" ::: "memory");  // t+1 landed
            else            asm volatile("s_waitcnt vmcnt(0)" ::: "memory");
            __builtin_amdgcn_sched_barrier(0);
            __builtin_amdgcn_s_barrier();   // everyone's t+1 landed + done reading bc
            __builtin_amdgcn_sched_barrier(0);
        }
        bc = (bc == 2) ? 0 : bc + 1;
        bnext = (bnext == 2) ? 0 : bnext + 1;
    }

    int fq = g * 4;
#pragma unroll
    for (int m = 0; m < 4; ++m)
#pragma unroll
        for (int n = 0; n < 4; ++n) {
            int row = m0 + wro + m * 16 + fq;
            int col = n0 + wco + n * 16 + fr;
#pragma unroll
            for (int r = 0; r < 4; ++r) {
                float v = acc[m][n][r];
                if (EPI == 0) {
                    outH[(long)(row + r) * N + col] = (__bf16)v;
                } else {
                    int part = col >> 10, c = col & 1023;
                    __bf16* dst = (part == 0) ? qOut : (part == 1) ? kOut : vOut;
                    dst[(long)(row + r) * 1024 + c] = (__bf16)v;
                }
            }
        }
}

// ---------------- swish-combine: hh = swish_bug(h1+b1) * (h2+b2) ----------------
__global__ __launch_bounds__(256) void k_hcomb(const __bf16* __restrict__ h12,
                                               const float* __restrict__ b1,
                                               const float* __restrict__ b2,
                                               __bf16* __restrict__ hh) {
    long total = (long)Mv * HIDP;
    long stride = (long)gridDim.x * 256 * 8;
    for (long i = ((long)blockIdx.x * 256 + threadIdx.x) * 8; i < total; i += stride) {
        int mrow = (int)(i / HIDP), j = (int)(i % HIDP);
        bf16x8 a = *(const bf16x8*)(h12 + (long)mrow * 5632 + j);
        bf16x8 bv = *(const bf16x8*)(h12 + (long)mrow * 5632 + 2816 + j);
        __bf16 o[8];
#pragma unroll
        for (int e = 0; e < 8; ++e) {
            bool in = (j + e < HIDv);
            float c1 = (float)a[e] + (in ? b1[j + e] : 0.f);
            float c2 = (float)bv[e] + (in ? b2[j + e] : 0.f);
            float sw = c1 * (1.0f + __expf(-c1));
            o[e] = (__bf16)(sw * c2);
        }
        *(bf16x8*)(hh + i) = *(bf16x8*)o;
    }
}

// ---------------- flash attention (unchanged from round 5) ----------------
__global__ __launch_bounds__(256) void k_attn(const __bf16* __restrict__ Q,
                                              const __bf16* __restrict__ KR,
                                              const __bf16* __restrict__ VT,
                                              __bf16* __restrict__ O) {
    __shared__ __align__(16) __bf16 Ks[64][64];
    __shared__ __align__(16) __bf16 Vs[64][64];
    __shared__ __align__(16) __bf16 Ps[4][16][64];
    int tid = threadIdx.x, lane = tid & 63, w = tid >> 6;
    int bh = blockIdx.x >> 5;
    int qt = 31 - (blockIdx.x & 31);
    int q0 = qt * 64;
    int b = bh >> 4, h = bh & 15;
    const long qbase = ((long)b * Tv) * Cv + h * HSv;
    const long kbase = (long)bh * Tv * 64;
    const long vbase = (long)bh * 64 * Tv;
    int fr = lane & 15, g = lane >> 4;
    int go = g * 8;
    int lr = lane >> 3, lc8 = (lane & 7) * 8;
    int xr = (fr & 7) << 4;
    int qrow = q0 + w * 16 + fr;
    bf16x8 qf0 = *(const bf16x8*)(Q + qbase + (long)qrow * Cv + go);
    bf16x8 qf1 = *(const bf16x8*)(Q + qbase + (long)qrow * Cv + 32 + go);

    const float SCL = 0.125f * 1.44269504f;
    f32x4 o[4] = {};
    float mrow = -INFINITY, lrow = 0.0f;

    for (int j0 = 0; j0 <= q0; j0 += 64) {
        __syncthreads();
#pragma unroll
        for (int i = 0; i < 2; ++i) {
            int rk = w * 16 + i * 8 + lr;
            gload_lds16(KR + kbase + (long)(j0 + rk) * 64 + lc8, &Ks[rk][lc8]);
            gload_lds16(VT + vbase + (long)rk * Tv + j0 + lc8, &Vs[rk][lc8]);
        }
        __syncthreads();
        f32x4 s4[4];
        __builtin_amdgcn_s_setprio(1);
#pragma unroll
        for (int kk = 0; kk < 4; ++kk) {
            int key = kk * 16 + fr;
            const char* krow = (const char*)&Ks[key][0];
            bf16x8 kf0 = *(const bf16x8*)(krow + ((go * 2) ^ ((key & 7) << 4)));
            bf16x8 kf1 = *(const bf16x8*)(krow + ((64 + go * 2) ^ ((key & 7) << 4)));
            f32x4 z = {};
            z = __builtin_amdgcn_mfma_f32_16x16x32_bf16(kf0, qf0, z, 0, 0, 0);
            z = __builtin_amdgcn_mfma_f32_16x16x32_bf16(kf1, qf1, z, 0, 0, 0);
            s4[kk] = z;
        }
        __builtin_amdgcn_s_setprio(0);
        bool diag = (j0 == q0);
        if (diag) {
            int qloc = w * 16 + fr;
#pragma unroll
            for (int kk = 0; kk < 4; ++kk)
#pragma unroll
                for (int r = 0; r < 4; ++r) {
                    int key = kk * 16 + g * 4 + r;
                    s4[kk][r] = (key > qloc) ? -INFINITY : s4[kk][r] * SCL;
                }
        } else {
#pragma unroll
            for (int kk = 0; kk < 4; ++kk)
#pragma unroll
                for (int r = 0; r < 4; ++r) s4[kk][r] *= SCL;
        }
        float pmax = s4[0][0];
#pragma unroll
        for (int kk = 0; kk < 4; ++kk)
#pragma unroll
            for (int r = 0; r < 4; ++r) pmax = fmaxf(pmax, s4[kk][r]);
        pmax = fmaxf(pmax, __shfl_xor(pmax, 16));
        pmax = fmaxf(pmax, __shfl_xor(pmax, 32));
        float mn = fmaxf(mrow, pmax);
        float alpha = exp2f(mrow - mn);
        mrow = mn;
        float rs = 0.0f;
#pragma unroll
        for (int kk = 0; kk < 4; ++kk)
#pragma unroll
            for (int r = 0; r < 4; ++r) {
                float pv = exp2f(s4[kk][r] - mn);
                s4[kk][r] = pv;
                rs += pv;
            }
        rs += __shfl_xor(rs, 16);
        rs += __shfl_xor(rs, 32);
        lrow = lrow * alpha + rs;
#pragma unroll
        for (int fb = 0; fb < 4; ++fb)
#pragma unroll
            for (int r = 0; r < 4; ++r) o[fb][r] *= alpha;
        char* prow = (char*)&Ps[w][fr][0];
#pragma unroll
        for (int kk = 0; kk < 4; ++kk) {
            __bf16 pk[4] = {(__bf16)s4[kk][0], (__bf16)s4[kk][1],
                            (__bf16)s4[kk][2], (__bf16)s4[kk][3]};
            *(ull*)(prow + ((kk * 32 + g * 8) ^ xr)) = *(ull*)pk;
        }
        const char* prd = prow;
        bf16x8 pa0 = *(const bf16x8*)(prd + ((g * 16) ^ xr));
        bf16x8 pa1 = *(const bf16x8*)(prd + ((64 + g * 16) ^ xr));
        __builtin_amdgcn_s_setprio(1);
#pragma unroll
        for (int fb = 0; fb < 4; ++fb) {
            int vrow = fb * 16 + fr;
            const char* vrd = (const char*)&Vs[vrow][0];
            bf16x8 v0 = *(const bf16x8*)(vrd + ((go * 2) ^ ((vrow & 7) << 4)));
            bf16x8 v1 = *(const bf16x8*)(vrd + ((64 + go * 2) ^ ((vrow & 7) << 4)));
            o[fb] = __builtin_amdgcn_mfma_f32_16x16x32_bf16(v0, pa0, o[fb], 0, 0, 0);
            o[fb] = __builtin_amdgcn_mfma_f32_16x16x32_bf16(v1, pa1, o[fb], 0, 0, 0);
        }
        __builtin_amdgcn_s_setprio(0);
    }
    float rl = 1.0f / lrow;
#pragma unroll
    for (int fb = 0; fb < 4; ++fb) {
        __bf16 ov[4];
#pragma unroll
        for (int r = 0; r < 4; ++r) ov[r] = (__bf16)(o[fb][r] * rl);
        *(ull*)(O + qbase + (long)qrow * Cv + fb * 16 + g * 4) = *(ull*)ov;
    }
}

// ---------------- launch ----------------
extern "C" void kernel_launch(void* const* d_in, const int* in_sizes, int n_in,
                              void* d_out, int out_size, void* d_ws, size_t ws_size,
                              hipStream_t stream) {
    const float* x    = (const float*)d_in[0];
    const float* ln1w = (const float*)d_in[1];
    const float* Wq   = (const float*)d_in[2];
    const float* Wk   = (const float*)d_in[3];
    const float* Wv   = (const float*)d_in[4];
    const float* Wo   = (const float*)d_in[5];
    const float* bo   = (const float*)d_in[6];
    const float* w1   = (const float*)d_in[7];
    const float* b1   = (const float*)d_in[8];
    const float* w2   = (const float*)d_in[9];
    const float* b2   = (const float*)d_in[10];
    const float* w3   = (const float*)d_in[11];
    const float* b3   = (const float*)d_in[12];
    const float* ln2w = (const float*)d_in[13];
    const float* cosT = (const float*)d_in[14];
    const float* sinT = (const float*)d_in[15];
    float* out = (float*)d_out;

    char* p = (char*)d_ws;
    auto alloc = [&](size_t bytes) {
        char* r = p;
        p += (bytes + 255) & ~(size_t)255;
        return r;
    };
    float*  x1f = (float*)alloc((size_t)Mv * Cv * 4);
    __bf16* qh  = (__bf16*)alloc((size_t)Mv * Cv * 2);
    __bf16* kh  = (__bf16*)alloc((size_t)Mv * Cv * 2);
    __bf16* vh  = (__bf16*)alloc((size_t)Mv * Cv * 2);
    __bf16* ah  = (__bf16*)alloc((size_t)Mv * Cv * 2);
    // h12 [Mv][5632] bf16 = 46.1 MB aliases x1f..ah (48 MB, all dead by FFN time)
    __bf16* h12 = (__bf16*)x1f;
    float*  x3f = (float*)alloc((size_t)Mv * Cv * 4);
    __bf16* x1h = (__bf16*)alloc((size_t)Mv * Cv * 2);
    __bf16* VT  = (__bf16*)x1h;                                   // x1h dead after QKV GEMM
    __bf16* x3h = (__bf16*)alloc((size_t)Mv * Cv * 2);
    __bf16* KR  = (__bf16*)alloc((size_t)Bv * Hv * Tv * HSv * 2);
    __bf16* hh  = (__bf16*)alloc((size_t)Mv * HIDP * 2);
    __bf16* wqkvh = (__bf16*)alloc((size_t)3072 * Cv * 2);
    __bf16* woh = (__bf16*)alloc((size_t)Cv * Cv * 2);
    __bf16* w1h = (__bf16*)alloc((size_t)HIDP * Cv * 2);
    __bf16* w2h = (__bf16*)alloc((size_t)HIDP * Cv * 2);   // contiguous after w1h: concat B
    __bf16* w3h = (__bf16*)alloc((size_t)Cv * HIDP * 2);

    const long nCC = (long)Cv * Cv;
    CastArgs ca;
    ca.seg[0] = {Wq, wqkvh,           nCC, nCC, 0, 0};
    ca.seg[1] = {Wk, wqkvh + nCC,     nCC, nCC, 0, 0};
    ca.seg[2] = {Wv, wqkvh + 2 * nCC, nCC, nCC, 0, 0};
    ca.seg[3] = {Wo, woh,             nCC, nCC, 0, 0};
    ca.seg[4] = {w1, w1h, (long)HIDv * Cv, (long)HIDP * Cv, 0, 0};
    ca.seg[5] = {w2, w2h, (long)HIDv * Cv, (long)HIDP * Cv, 0, 0};
    ca.seg[6] = {w3, w3h, (long)Cv * HIDv, (long)Cv * HIDP, HIDv, HIDP};
    k_castall<<<2048, 256, 0, stream>>>(ca);

    k_rmsnorm<<<Mv, 256, 0, stream>>>(x, ln1w, x1f, x1h);

    // QKV: pipelined GEMM, N = 3072
    k_gemm3<4><<<dim3(12, 32), 512, 0, stream>>>(x1h, wqkvh, Mv, 3072, Cv,
        nullptr, qh, kh, vh);

    k_rope<<<(Mv * 512 + 255) / 256, 256, 0, stream>>>(qh, kh, KR, cosT, sinT);
    k_vtrans<<<dim3(Tv / 64, Bv * Hv), 256, 0, stream>>>(vh, VT);

    k_attn<<<1024, 256, 0, stream>>>(qh, KR, VT, ah);

    // x2 = x1 + attn @ Wo^T + bo  (into x1f)
    k_gemm<64, 1><<<dim3(8, 64), 256, 0, stream>>>(ah, woh, Mv, Cv, Cv,
        x1f, bo, x1f);

    k_rmsnorm<<<Mv, 256, 0, stream>>>(x1f, ln2w, x3f, x3h);

    // FFN12: h12 = x3 @ [w1;w2]^T  (N = 5632, pipelined; h12 overlays dead x1f..ah)
    k_gemm3<0><<<dim3(22, 32), 512, 0, stream>>>(x3h, w1h, Mv, 5632, Cv,
        h12, nullptr, nullptr, nullptr);
    // hh = swish_bug(h1+b1) * (h2+b2)
    k_hcomb<<<2048, 256, 0, stream>>>(h12, b1, b2, hh);

    // out = x3 + hh @ w3^T + b3
    k_gemm<64, 1><<<dim3(8, 64), 256, 0, stream>>>(hh, w3h, Mv, Cv, HIDP,
        out, b3, x3f);
}

// Round 7
// 345.847 us; speedup vs baseline: 1.0577x; 1.0577x over previous
//
#include <hip/hip_runtime.h>
#include <hip/hip_bf16.h>

#define Bv 2
#define Tv 2048
#define Cv 1024
#define Hv 16
#define HSv 64
#define HIDv 2730
#define HIDP 2816
#define Mv 4096

using bf16x8 = __attribute__((ext_vector_type(8))) __bf16;
using f32x4  = __attribute__((ext_vector_type(4))) float;
typedef unsigned long long ull;

__device__ __forceinline__ void gload_lds16(const void* g, void* l) {
    auto gp = (const __attribute__((address_space(1))) unsigned int*)(unsigned long long)(uintptr_t)g;
    auto lp = (__attribute__((address_space(3))) unsigned int*)(unsigned int)(uintptr_t)l;
    __builtin_amdgcn_global_load_lds(gp, lp, 16, 0, 0);
}

// ---------------- fused weight cast ----------------
struct CastSeg { const float* s; __bf16* d; long nsrc; long ntot; int sc; int dc; };
struct CastArgs { CastSeg seg[7]; };

__global__ __launch_bounds__(256) void k_castall(CastArgs a) {
    long gid = (long)blockIdx.x * 256 + threadIdx.x;
    long gstr = (long)gridDim.x * 256;
#pragma unroll 1
    for (int g = 0; g < 7; ++g) {
        CastSeg sg = a.seg[g];
        if (sg.sc == 0) {
            long n4 = sg.ntot >> 2;
            for (long i = gid; i < n4; i += gstr) {
                long base = i * 4;
                float4 v = {0.f, 0.f, 0.f, 0.f};
                if (base < sg.nsrc) v = *(const float4*)(sg.s + base);
                __bf16 o[4] = {(__bf16)v.x, (__bf16)v.y, (__bf16)v.z, (__bf16)v.w};
                *(ull*)(sg.d + base) = *(ull*)o;
            }
        } else {
            for (long i = gid; i < sg.ntot; i += gstr) {
                int r = (int)(i / sg.dc), c = (int)(i % sg.dc);
                sg.d[i] = (c < sg.sc) ? (__bf16)sg.s[(long)r * sg.sc + c] : (__bf16)0.0f;
            }
        }
    }
}

// ---------------- rmsnorm ----------------
__global__ __launch_bounds__(256) void k_rmsnorm(const float* __restrict__ x,
                                                 const float* __restrict__ w,
                                                 float* __restrict__ yf,
                                                 __bf16* __restrict__ yh) {
    int row = blockIdx.x;
    const float4* xr = (const float4*)(x + (size_t)row * Cv);
    float4 a = xr[threadIdx.x];
    float ss = a.x * a.x + a.y * a.y + a.z * a.z + a.w * a.w;
#pragma unroll
    for (int m = 1; m < 64; m <<= 1) ss += __shfl_xor(ss, m);
    __shared__ float red[4];
    if ((threadIdx.x & 63) == 0) red[threadIdx.x >> 6] = ss;
    __syncthreads();
    float tot = red[0] + red[1] + red[2] + red[3];
    float sc = rsqrtf(tot * (1.0f / Cv) + 1e-6f);
    float4 wv = ((const float4*)w)[threadIdx.x];
    float4 o;
    o.x = a.x * sc * wv.x; o.y = a.y * sc * wv.y;
    o.z = a.z * sc * wv.z; o.w = a.w * sc * wv.w;
    ((float4*)(yf + (size_t)row * Cv))[threadIdx.x] = o;
    __bf16* yp = yh + (size_t)row * Cv + threadIdx.x * 4;
    yp[0] = (__bf16)o.x; yp[1] = (__bf16)o.y; yp[2] = (__bf16)o.z; yp[3] = (__bf16)o.w;
}

// ---------------- RoPE: Q in place; K -> KR[bh][t][64] pre-swizzled ----------------
__global__ void k_rope(__bf16* __restrict__ Q, const __bf16* __restrict__ Kin,
                       __bf16* __restrict__ KR,
                       const float* __restrict__ cosT, const float* __restrict__ sinT) {
    long total = (long)Mv * 512;
    long i = (long)blockIdx.x * blockDim.x + threadIdx.x;
    if (i >= total) return;
    int row = (int)(i >> 9);
    int p = (int)(i & 511);
    int h = p >> 5, ii = p & 31;
    int t = row & (Tv - 1), b = row >> 11;
    float c = cosT[t * 32 + ii], s = sinT[t * 32 + ii];
    long idx = (long)row * Cv + h * 64 + 2 * ii;
    float x0 = (float)Q[idx], x1 = (float)Q[idx + 1];
    Q[idx]     = (__bf16)(x0 * c - x1 * s);
    Q[idx + 1] = (__bf16)(x0 * s + x1 * c);
    float y0 = (float)Kin[idx], y1 = (float)Kin[idx + 1];
    __bf16 k0 = (__bf16)(y0 * c - y1 * s);
    __bf16 k1 = (__bf16)(y0 * s + y1 * c);
    int bh = b * 16 + h;
    int colb = (4 * ii) ^ ((t & 7) << 4);
    __bf16 pk[2] = {k0, k1};
    *(unsigned int*)((char*)(KR + ((long)bh * Tv + t) * 64) + colb) = *(unsigned int*)pk;
}

// ---------------- V transpose: VT[bh][f][t], pre-swizzled per 64-key tile ----------------
__global__ __launch_bounds__(256) void k_vtrans(const __bf16* __restrict__ V,
                                                __bf16* __restrict__ VT) {
    __shared__ __bf16 Ts[64][72];
    int t0 = blockIdx.x * 64;
    int bh = blockIdx.y, b = bh >> 4, h = bh & 15;
    const long base = ((long)b * Tv) * Cv + h * 64;
    int tid = threadIdx.x;
    int rr = tid >> 3, cc = (tid & 7) * 8;
#pragma unroll
    for (int it = 0; it < 2; ++it) {
        int row = it * 32 + rr;
        *(int4*)&Ts[row][cc] = *(const int4*)(V + base + (long)(t0 + row) * Cv + cc);
    }
    __syncthreads();
#pragma unroll
    for (int it = 0; it < 2; ++it) {
        int f = it * 32 + rr;
        int tcol = cc ^ ((f & 7) << 3);
        __bf16 tmp[8];
#pragma unroll
        for (int j = 0; j < 8; ++j) tmp[j] = Ts[tcol + j][f];
        *(int4*)(VT + ((long)bh * 64 + f) * Tv + t0 + cc) = *(int4*)tmp;
    }
}

// ---------------- GEMM: C[M,N] = A[M,K] @ B[N,K]^T, m97 structure + XCD swizzle ----------------
// EPI 1: outF = acc (+bias[col]) (+resid[idx]) ; EPI 4: route cols to q/k/v
template <int BM, int EPI>
__global__ __launch_bounds__(256) void k_gemm(
    const __bf16* __restrict__ A, const __bf16* __restrict__ Bm,
    int M, int N, int K,
    float* __restrict__ outF,
    const float* __restrict__ bias,
    const float* __restrict__ resid,
    __bf16* __restrict__ qOut, __bf16* __restrict__ kOut, __bf16* __restrict__ vOut) {
    constexpr int NN = (BM == 128) ? 4 : 2;
    __shared__ __align__(16) __bf16 As[BM][64];
    __shared__ __align__(16) __bf16 Bs[128][64];
    int tid = threadIdx.x, lane = tid & 63, wave = tid >> 6;
    // XCD-aware bijective swizzle (all grids are multiples of 8)
    int gx = gridDim.x;
    int flat = blockIdx.y * gx + blockIdx.x;
    int nwg = gx * gridDim.y;
    int orig = (flat & 7) * (nwg >> 3) + (flat >> 3);
    int m0 = (orig / gx) * BM, n0 = (orig % gx) * 128;
    int wro = (BM == 128) ? (wave >> 1) * 64 : 0;
    int wco = (BM == 128) ? (wave & 1) * 64 : wave * 32;
    int fr = lane & 15, fo = (lane >> 4) * 8;
    int lr = lane >> 3, lc = (lane & 7) * 8;
    f32x4 acc[4][NN] = {};
    for (int k0 = 0; k0 < K; k0 += 64) {
        __syncthreads();
        int arow0 = wave * (BM / 4);
#pragma unroll
        for (int i = 0; i < BM / 32; ++i) {
            int r = arow0 + i * 8 + lr;
            gload_lds16(A + (long)(m0 + r) * K + k0 + lc, &As[r][lc]);
        }
        int brow0 = wave * 32;
#pragma unroll
        for (int i = 0; i < 4; ++i) {
            int r = brow0 + i * 8 + lr;
            gload_lds16(Bm + (long)(n0 + r) * K + k0 + lc, &Bs[r][lc]);
        }
        __syncthreads();
#pragma unroll
        for (int s = 0; s < 2; ++s) {
            bf16x8 af[4], bf[NN];
#pragma unroll
            for (int m = 0; m < 4; ++m)
                af[m] = *(const bf16x8*)(&As[wro + m * 16 + fr][s * 32 + fo]);
#pragma unroll
            for (int n = 0; n < NN; ++n)
                bf[n] = *(const bf16x8*)(&Bs[wco + n * 16 + fr][s * 32 + fo]);
#pragma unroll
            for (int m = 0; m < 4; ++m)
#pragma unroll
                for (int n = 0; n < NN; ++n)
                    acc[m][n] = __builtin_amdgcn_mfma_f32_16x16x32_bf16(af[m], bf[n], acc[m][n], 0, 0, 0);
        }
    }
    int fq = (lane >> 4) * 4;
#pragma unroll
    for (int m = 0; m < 4; ++m)
#pragma unroll
        for (int n = 0; n < NN; ++n) {
            int row = m0 + wro + m * 16 + fq;
            int col = n0 + wco + n * 16 + fr;
#pragma unroll
            for (int r = 0; r < 4; ++r) {
                float v = acc[m][n][r];
                long idx = (long)(row + r) * N + col;
                if (EPI == 1) {
                    if (bias) v += bias[col];
                    if (resid) v += resid[idx];
                    outF[idx] = v;
                } else {
                    int part = col >> 10, c = col & 1023;
                    __bf16* dst = (part == 0) ? qOut : (part == 1) ? kOut : vOut;
                    dst[(long)(row + r) * 1024 + c] = (__bf16)v;
                }
            }
        }
}

// ---------------- fused FFN1+FFN2 (f32 accs, + XCD swizzle) ----------------
__global__ __launch_bounds__(256) void k_ffn(const __bf16* __restrict__ A,
                                             const __bf16* __restrict__ B1,
                                             const __bf16* __restrict__ B2,
                                             const float* __restrict__ b1,
                                             const float* __restrict__ b2,
                                             __bf16* __restrict__ outH) {
    __shared__ __align__(16) __bf16 As[128][64];
    __shared__ __align__(16) __bf16 B1s[64][64];
    __shared__ __align__(16) __bf16 B2s[64][64];
    int tid = threadIdx.x, lane = tid & 63, wave = tid >> 6;
    int gx = gridDim.x;
    int flat = blockIdx.y * gx + blockIdx.x;
    int nwg = gx * gridDim.y;
    int orig = (flat & 7) * (nwg >> 3) + (flat >> 3);
    int m0 = (orig / gx) * 128, n0 = (orig % gx) * 64;
    int fr = lane & 15, fo = (lane >> 4) * 8;
    int lr = lane >> 3, lc = (lane & 7) * 8;
    f32x4 acc1[2][4] = {}, acc2[2][4] = {};
    for (int k0 = 0; k0 < Cv; k0 += 64) {
        __syncthreads();
#pragma unroll
        for (int i = 0; i < 4; ++i) {
            int r = wave * 32 + i * 8 + lr;
            gload_lds16(A + (long)(m0 + r) * Cv + k0 + lc, &As[r][lc]);
        }
#pragma unroll
        for (int i = 0; i < 2; ++i) {
            int r = wave * 16 + i * 8 + lr;
            gload_lds16(B1 + (long)(n0 + r) * Cv + k0 + lc, &B1s[r][lc]);
            gload_lds16(B2 + (long)(n0 + r) * Cv + k0 + lc, &B2s[r][lc]);
        }
        __syncthreads();
#pragma unroll
        for (int s = 0; s < 2; ++s) {
            bf16x8 af[2], b1f[4], b2f[4];
#pragma unroll
            for (int m = 0; m < 2; ++m)
                af[m] = *(const bf16x8*)(&As[wave * 32 + m * 16 + fr][s * 32 + fo]);
#pragma unroll
            for (int n = 0; n < 4; ++n) {
                b1f[n] = *(const bf16x8*)(&B1s[n * 16 + fr][s * 32 + fo]);
                b2f[n] = *(const bf16x8*)(&B2s[n * 16 + fr][s * 32 + fo]);
            }
#pragma unroll
            for (int m = 0; m < 2; ++m)
#pragma unroll
                for (int n = 0; n < 4; ++n) {
                    acc1[m][n] = __builtin_amdgcn_mfma_f32_16x16x32_bf16(af[m], b1f[n], acc1[m][n], 0, 0, 0);
                    acc2[m][n] = __builtin_amdgcn_mfma_f32_16x16x32_bf16(af[m], b2f[n], acc2[m][n], 0, 0, 0);
                }
        }
    }
    int fq = (lane >> 4) * 4;
#pragma unroll
    for (int m = 0; m < 2; ++m)
#pragma unroll
        for (int n = 0; n < 4; ++n) {
            int row = m0 + wave * 32 + m * 16 + fq;
            int col = n0 + n * 16 + fr;
            float b1v = (col < HIDv) ? b1[col] : 0.0f;
            float b2v = (col < HIDv) ? b2[col] : 0.0f;
#pragma unroll
            for (int r = 0; r < 4; ++r) {
                float c1 = acc1[m][n][r] + b1v;
                float c2 = acc2[m][n][r] + b2v;
                float sw = c1 * (1.0f + __expf(-c1));
                outH[(long)(row + r) * HIDP + col] = (__bf16)(sw * c2);
            }
        }
}

// ---------------- flash attention: swapped MFMA + dbuf(1 barrier/tile) + defer-max ----------------
__global__ __launch_bounds__(256) void k_attn(const __bf16* __restrict__ Q,
                                              const __bf16* __restrict__ KR,
                                              const __bf16* __restrict__ VT,
                                              __bf16* __restrict__ O) {
    __shared__ __align__(16) __bf16 Ks[2][64][64];
    __shared__ __align__(16) __bf16 Vs[2][64][64];
    __shared__ __align__(16) __bf16 Ps[4][16][64];
    int tid = threadIdx.x, lane = tid & 63, w = tid >> 6;
    int bh = blockIdx.x >> 5;
    int qt = 31 - (blockIdx.x & 31);          // heavy blocks first
    int q0 = qt * 64;
    int b = bh >> 4, h = bh & 15;
    const long qbase = ((long)b * Tv) * Cv + h * HSv;
    const long kbase = (long)bh * Tv * 64;
    const long vbase = (long)bh * 64 * Tv;
    int fr = lane & 15, g = lane >> 4;
    int go = g * 8;
    int lr = lane >> 3, lc8 = (lane & 7) * 8;
    int xr = (fr & 7) << 4;
    int qrow = q0 + w * 16 + fr;
    bf16x8 qf0 = *(const bf16x8*)(Q + qbase + (long)qrow * Cv + go);
    bf16x8 qf1 = *(const bf16x8*)(Q + qbase + (long)qrow * Cv + 32 + go);

    const float SCL = 0.125f * 1.44269504f;
    f32x4 o[4] = {};
    float mrow = -INFINITY, lrow = 0.0f;

    auto stage = [&](int j0, int bufi) {
#pragma unroll
        for (int i = 0; i < 2; ++i) {
            int rk = w * 16 + i * 8 + lr;
            gload_lds16(KR + kbase + (long)(j0 + rk) * 64 + lc8, &Ks[bufi][rk][lc8]);
            gload_lds16(VT + vbase + (long)rk * Tv + j0 + lc8, &Vs[bufi][rk][lc8]);
        }
    };

    stage(0, 0);
    for (int t = 0; t <= qt; ++t) {
        int cur = t & 1;
        __syncthreads();                    // drains this wave's stage(t); all waves aligned
        if (t < qt) stage((t + 1) * 64, cur ^ 1);   // flies under compute of tile t
        // ---- QK^T (swapped: A=K, B=Q -> D[key][qrow]) ----
        f32x4 s4[4];
        __builtin_amdgcn_s_setprio(1);
#pragma unroll
        for (int kk = 0; kk < 4; ++kk) {
            int key = kk * 16 + fr;
            const char* krow = (const char*)&Ks[cur][key][0];
            bf16x8 kf0 = *(const bf16x8*)(krow + ((go * 2) ^ ((key & 7) << 4)));
            bf16x8 kf1 = *(const bf16x8*)(krow + ((64 + go * 2) ^ ((key & 7) << 4)));
            f32x4 z = {};
            z = __builtin_amdgcn_mfma_f32_16x16x32_bf16(kf0, qf0, z, 0, 0, 0);
            z = __builtin_amdgcn_mfma_f32_16x16x32_bf16(kf1, qf1, z, 0, 0, 0);
            s4[kk] = z;
        }
        __builtin_amdgcn_s_setprio(0);
        // ---- scale + causal mask ----
        bool diag = (t == qt);
        if (diag) {
            int qloc = w * 16 + fr;
#pragma unroll
            for (int kk = 0; kk < 4; ++kk)
#pragma unroll
                for (int r = 0; r < 4; ++r) {
                    int key = kk * 16 + g * 4 + r;
                    s4[kk][r] = (key > qloc) ? -INFINITY : s4[kk][r] * SCL;
                }
        } else {
#pragma unroll
            for (int kk = 0; kk < 4; ++kk)
#pragma unroll
                for (int r = 0; r < 4; ++r) s4[kk][r] *= SCL;
        }
        // ---- online softmax (lane-local row) + defer-max ----
        float pmax = s4[0][0];
#pragma unroll
        for (int kk = 0; kk < 4; ++kk)
#pragma unroll
            for (int r = 0; r < 4; ++r) pmax = fmaxf(pmax, s4[kk][r]);
        pmax = fmaxf(pmax, __shfl_xor(pmax, 16));
        pmax = fmaxf(pmax, __shfl_xor(pmax, 32));
        bool keep = __all(pmax - mrow <= 8.0f);   // P bounded by 2^8, f32 l has headroom
        if (!keep) {
            float mn = fmaxf(mrow, pmax);
            float alpha = exp2f(mrow - mn);
            mrow = mn;
            lrow *= alpha;
#pragma unroll
            for (int fb = 0; fb < 4; ++fb)
#pragma unroll
                for (int r = 0; r < 4; ++r) o[fb][r] *= alpha;
        }
        float rs = 0.0f;
#pragma unroll
        for (int kk = 0; kk < 4; ++kk)
#pragma unroll
            for (int r = 0; r < 4; ++r) {
                float pv = exp2f(s4[kk][r] - mrow);
                s4[kk][r] = pv;
                rs += pv;
            }
        rs += __shfl_xor(rs, 16);
        rs += __shfl_xor(rs, 32);
        lrow += rs;
        // ---- P -> LDS (per-wave, swizzled) ----
        char* prow = (char*)&Ps[w][fr][0];
#pragma unroll
        for (int kk = 0; kk < 4; ++kk) {
            __bf16 pk[4] = {(__bf16)s4[kk][0], (__bf16)s4[kk][1],
                            (__bf16)s4[kk][2], (__bf16)s4[kk][3]};
            *(ull*)(prow + ((kk * 32 + g * 8) ^ xr)) = *(ull*)pk;
        }
        // ---- PV (swapped: A=V^T, B=P^T -> D[f][qrow]) ----
        const char* prd = prow;
        bf16x8 pa0 = *(const bf16x8*)(prd + ((g * 16) ^ xr));
        bf16x8 pa1 = *(const bf16x8*)(prd + ((64 + g * 16) ^ xr));
        __builtin_amdgcn_s_setprio(1);
#pragma unroll
        for (int fb = 0; fb < 4; ++fb) {
            int vrow = fb * 16 + fr;
            const char* vrd = (const char*)&Vs[cur][vrow][0];
            bf16x8 v0 = *(const bf16x8*)(vrd + ((go * 2) ^ ((vrow & 7) << 4)));
            bf16x8 v1 = *(const bf16x8*)(vrd + ((64 + go * 2) ^ ((vrow & 7) << 4)));
            o[fb] = __builtin_amdgcn_mfma_f32_16x16x32_bf16(v0, pa0, o[fb], 0, 0, 0);
            o[fb] = __builtin_amdgcn_mfma_f32_16x16x32_bf16(v1, pa1, o[fb], 0, 0, 0);
        }
        __builtin_amdgcn_s_setprio(0);
    }
    float rl = 1.0f / lrow;
#pragma unroll
    for (int fb = 0; fb < 4; ++fb) {
        __bf16 ov[4];
#pragma unroll
        for (int r = 0; r < 4; ++r) ov[r] = (__bf16)(o[fb][r] * rl);
        *(ull*)(O + qbase + (long)qrow * Cv + fb * 16 + g * 4) = *(ull*)ov;
    }
}

// ---------------- launch ----------------
extern "C" void kernel_launch(void* const* d_in, const int* in_sizes, int n_in,
                              void* d_out, int out_size, void* d_ws, size_t ws_size,
                              hipStream_t stream) {
    const float* x    = (const float*)d_in[0];
    const float* ln1w = (const float*)d_in[1];
    const float* Wq   = (const float*)d_in[2];
    const float* Wk   = (const float*)d_in[3];
    const float* Wv   = (const float*)d_in[4];
    const float* Wo   = (const float*)d_in[5];
    const float* bo   = (const float*)d_in[6];
    const float* w1   = (const float*)d_in[7];
    const float* b1   = (const float*)d_in[8];
    const float* w2   = (const float*)d_in[9];
    const float* b2   = (const float*)d_in[10];
    const float* w3   = (const float*)d_in[11];
    const float* b3   = (const float*)d_in[12];
    const float* ln2w = (const float*)d_in[13];
    const float* cosT = (const float*)d_in[14];
    const float* sinT = (const float*)d_in[15];
    float* out = (float*)d_out;

    char* p = (char*)d_ws;
    auto alloc = [&](size_t bytes) {
        char* r = p;
        p += (bytes + 255) & ~(size_t)255;
        return r;
    };
    float*  x1f = (float*)alloc((size_t)Mv * Cv * 4);
    __bf16* qh  = (__bf16*)alloc((size_t)Mv * Cv * 2);
    __bf16* kh  = (__bf16*)alloc((size_t)Mv * Cv * 2);
    __bf16* vh  = (__bf16*)alloc((size_t)Mv * Cv * 2);
    __bf16* ah  = (__bf16*)alloc((size_t)Mv * Cv * 2);
    float*  x3f = (float*)alloc((size_t)Mv * Cv * 4);
    __bf16* x1h = (__bf16*)alloc((size_t)Mv * Cv * 2);
    __bf16* VT  = (__bf16*)x1h;                                   // x1h dead after QKV GEMM
    __bf16* x3h = (__bf16*)alloc((size_t)Mv * Cv * 2);
    __bf16* KR  = (__bf16*)alloc((size_t)Bv * Hv * Tv * HSv * 2);
    __bf16* hh  = (__bf16*)alloc((size_t)Mv * HIDP * 2);
    __bf16* wqkvh = (__bf16*)alloc((size_t)3072 * Cv * 2);
    __bf16* woh = (__bf16*)alloc((size_t)Cv * Cv * 2);
    __bf16* w1h = (__bf16*)alloc((size_t)HIDP * Cv * 2);
    __bf16* w2h = (__bf16*)alloc((size_t)HIDP * Cv * 2);
    __bf16* w3h = (__bf16*)alloc((size_t)Cv * HIDP * 2);

    const long nCC = (long)Cv * Cv;
    CastArgs ca;
    ca.seg[0] = {Wq, wqkvh,           nCC, nCC, 0, 0};
    ca.seg[1] = {Wk, wqkvh + nCC,     nCC, nCC, 0, 0};
    ca.seg[2] = {Wv, wqkvh + 2 * nCC, nCC, nCC, 0, 0};
    ca.seg[3] = {Wo, woh,             nCC, nCC, 0, 0};
    ca.seg[4] = {w1, w1h, (long)HIDv * Cv, (long)HIDP * Cv, 0, 0};
    ca.seg[5] = {w2, w2h, (long)HIDv * Cv, (long)HIDP * Cv, 0, 0};
    ca.seg[6] = {w3, w3h, (long)Cv * HIDv, (long)Cv * HIDP, HIDv, HIDP};
    k_castall<<<2048, 256, 0, stream>>>(ca);

    k_rmsnorm<<<Mv, 256, 0, stream>>>(x, ln1w, x1f, x1h);

    // QKV: N = 3072 (768 blocks, 3/CU)
    k_gemm<128, 4><<<dim3(24, 32), 256, 0, stream>>>(x1h, wqkvh, Mv, 3072, Cv,
        nullptr, nullptr, nullptr, qh, kh, vh);

    k_rope<<<(Mv * 512 + 255) / 256, 256, 0, stream>>>(qh, kh, KR, cosT, sinT);
    k_vtrans<<<dim3(Tv / 64, Bv * Hv), 256, 0, stream>>>(vh, VT);

    k_attn<<<1024, 256, 0, stream>>>(qh, KR, VT, ah);

    // x2 = x1 + attn @ Wo^T + bo  (into x1f)
    k_gemm<64, 1><<<dim3(8, 64), 256, 0, stream>>>(ah, woh, Mv, Cv, Cv,
        x1f, bo, x1f, nullptr, nullptr, nullptr);

    k_rmsnorm<<<Mv, 256, 0, stream>>>(x1f, ln2w, x3f, x3h);

    // hh = swish_bug(x3@w1^T + b1) * (x3@w2^T + b2)  (f32 accs, fused)
    k_ffn<<<dim3(HIDP / 64, 32), 256, 0, stream>>>(x3h, w1h, w2h, b1, b2, hh);

    // out = x3 + hh @ w3^T + b3
    k_gemm<64, 1><<<dim3(8, 64), 256, 0, stream>>>(hh, w3h, Mv, Cv, HIDP,
        out, b3, x3f, nullptr, nullptr, nullptr);
}

// Round 8
// 299.926 us; speedup vs baseline: 1.2197x; 1.1531x over previous
//
#include <hip/hip_runtime.h>
#include <hip/hip_bf16.h>

#define Bv 2
#define Tv 2048
#define Cv 1024
#define Hv 16
#define HSv 64
#define HIDv 2730
#define HIDP 2816
#define Mv 4096

using bf16x8 = __attribute__((ext_vector_type(8))) __bf16;
using f32x4  = __attribute__((ext_vector_type(4))) float;
typedef unsigned long long ull;

__device__ __forceinline__ void gload_lds16(const void* g, void* l) {
    auto gp = (const __attribute__((address_space(1))) unsigned int*)(unsigned long long)(uintptr_t)g;
    auto lp = (__attribute__((address_space(3))) unsigned int*)(unsigned int)(uintptr_t)l;
    __builtin_amdgcn_global_load_lds(gp, lp, 16, 0, 0);
}

// ---------------- fused weight cast ----------------
struct CastSeg { const float* s; __bf16* d; long nsrc; long ntot; int sc; int dc; };
struct CastArgs { CastSeg seg[7]; };

__global__ __launch_bounds__(256) void k_castall(CastArgs a) {
    long gid = (long)blockIdx.x * 256 + threadIdx.x;
    long gstr = (long)gridDim.x * 256;
#pragma unroll 1
    for (int g = 0; g < 7; ++g) {
        CastSeg sg = a.seg[g];
        if (sg.sc == 0) {
            long n4 = sg.ntot >> 2;
            for (long i = gid; i < n4; i += gstr) {
                long base = i * 4;
                float4 v = {0.f, 0.f, 0.f, 0.f};
                if (base < sg.nsrc) v = *(const float4*)(sg.s + base);
                __bf16 o[4] = {(__bf16)v.x, (__bf16)v.y, (__bf16)v.z, (__bf16)v.w};
                *(ull*)(sg.d + base) = *(ull*)o;
            }
        } else {
            for (long i = gid; i < sg.ntot; i += gstr) {
                int r = (int)(i / sg.dc), c = (int)(i % sg.dc);
                sg.d[i] = (c < sg.sc) ? (__bf16)sg.s[(long)r * sg.sc + c] : (__bf16)0.0f;
            }
        }
    }
}

// ---------------- rmsnorm ----------------
__global__ __launch_bounds__(256) void k_rmsnorm(const float* __restrict__ x,
                                                 const float* __restrict__ w,
                                                 float* __restrict__ yf,
                                                 __bf16* __restrict__ yh) {
    int row = blockIdx.x;
    const float4* xr = (const float4*)(x + (size_t)row * Cv);
    float4 a = xr[threadIdx.x];
    float ss = a.x * a.x + a.y * a.y + a.z * a.z + a.w * a.w;
#pragma unroll
    for (int m = 1; m < 64; m <<= 1) ss += __shfl_xor(ss, m);
    __shared__ float red[4];
    if ((threadIdx.x & 63) == 0) red[threadIdx.x >> 6] = ss;
    __syncthreads();
    float tot = red[0] + red[1] + red[2] + red[3];
    float sc = rsqrtf(tot * (1.0f / Cv) + 1e-6f);
    float4 wv = ((const float4*)w)[threadIdx.x];
    float4 o;
    o.x = a.x * sc * wv.x; o.y = a.y * sc * wv.y;
    o.z = a.z * sc * wv.z; o.w = a.w * sc * wv.w;
    ((float4*)(yf + (size_t)row * Cv))[threadIdx.x] = o;
    __bf16* yp = yh + (size_t)row * Cv + threadIdx.x * 4;
    yp[0] = (__bf16)o.x; yp[1] = (__bf16)o.y; yp[2] = (__bf16)o.z; yp[3] = (__bf16)o.w;
}

// ---------------- RoPE: Q in place; K -> KR[bh][t][64] pre-swizzled ----------------
__global__ void k_rope(__bf16* __restrict__ Q, const __bf16* __restrict__ Kin,
                       __bf16* __restrict__ KR,
                       const float* __restrict__ cosT, const float* __restrict__ sinT) {
    long total = (long)Mv * 512;
    long i = (long)blockIdx.x * blockDim.x + threadIdx.x;
    if (i >= total) return;
    int row = (int)(i >> 9);
    int p = (int)(i & 511);
    int h = p >> 5, ii = p & 31;
    int t = row & (Tv - 1), b = row >> 11;
    float c = cosT[t * 32 + ii], s = sinT[t * 32 + ii];
    long idx = (long)row * Cv + h * 64 + 2 * ii;
    float x0 = (float)Q[idx], x1 = (float)Q[idx + 1];
    Q[idx]     = (__bf16)(x0 * c - x1 * s);
    Q[idx + 1] = (__bf16)(x0 * s + x1 * c);
    float y0 = (float)Kin[idx], y1 = (float)Kin[idx + 1];
    __bf16 k0 = (__bf16)(y0 * c - y1 * s);
    __bf16 k1 = (__bf16)(y0 * s + y1 * c);
    int bh = b * 16 + h;
    int colb = (4 * ii) ^ ((t & 7) << 4);
    __bf16 pk[2] = {k0, k1};
    *(unsigned int*)((char*)(KR + ((long)bh * Tv + t) * 64) + colb) = *(unsigned int*)pk;
}

// ---------------- V transpose: VT[bh][f][t], pre-swizzled per 64-key tile ----------------
__global__ __launch_bounds__(256) void k_vtrans(const __bf16* __restrict__ V,
                                                __bf16* __restrict__ VT) {
    __shared__ __bf16 Ts[64][72];
    int t0 = blockIdx.x * 64;
    int bh = blockIdx.y, b = bh >> 4, h = bh & 15;
    const long base = ((long)b * Tv) * Cv + h * 64;
    int tid = threadIdx.x;
    int rr = tid >> 3, cc = (tid & 7) * 8;
#pragma unroll
    for (int it = 0; it < 2; ++it) {
        int row = it * 32 + rr;
        *(int4*)&Ts[row][cc] = *(const int4*)(V + base + (long)(t0 + row) * Cv + cc);
    }
    __syncthreads();
#pragma unroll
    for (int it = 0; it < 2; ++it) {
        int f = it * 32 + rr;
        int tcol = cc ^ ((f & 7) << 3);
        __bf16 tmp[8];
#pragma unroll
        for (int j = 0; j < 8; ++j) tmp[j] = Ts[tcol + j][f];
        *(int4*)(VT + ((long)bh * 64 + f) * Tv + t0 + cc) = *(int4*)tmp;
    }
}

// ---------------- GEMM (m97 structure + T2 source-XOR swizzle + XCD-chunk m-fast) ----------------
// 1-D grid. EPI 1: outF = acc (+bias)(+resid) ; EPI 4: route cols to q/k/v
template <int BM, int EPI>
__global__ __launch_bounds__(256) void k_gemm(
    const __bf16* __restrict__ A, const __bf16* __restrict__ Bm,
    int M, int N, int K,
    float* __restrict__ outF,
    const float* __restrict__ bias,
    const float* __restrict__ resid,
    __bf16* __restrict__ qOut, __bf16* __restrict__ kOut, __bf16* __restrict__ vOut) {
    constexpr int NN = (BM == 128) ? 4 : 2;
    __shared__ __align__(16) __bf16 As[BM][64];
    __shared__ __align__(16) __bf16 Bs[128][64];
    int tid = threadIdx.x, lane = tid & 63, wave = tid >> 6;
    // XCD-chunk (bijective, nwg % 8 == 0) + m-fast decode: B n-panel stays L2-resident
    int nm = M / BM;
    int nwg = nm * (N >> 7);
    int flat = blockIdx.x;
    int orig = (flat & 7) * (nwg >> 3) + (flat >> 3);
    int m0 = (orig % nm) * BM;
    int n0 = (orig / nm) * 128;
    int wro = (BM == 128) ? (wave >> 1) * 64 : 0;
    int wco = (BM == 128) ? (wave & 1) * 64 : wave * 32;
    int fr = lane & 15, fo2 = (lane >> 4) * 16;   // frag byte offset base
    int lr = lane >> 3, lc = (lane & 7) * 8;
    f32x4 acc[4][NN] = {};
    for (int k0 = 0; k0 < K; k0 += 64) {
        __syncthreads();
        int arow0 = wave * (BM / 4);
#pragma unroll
        for (int i = 0; i < BM / 32; ++i) {
            int r = arow0 + i * 8 + lr;
            gload_lds16(A + (long)(m0 + r) * K + k0 + (lc ^ ((r & 7) << 3)), &As[r][lc]);
        }
        int brow0 = wave * 32;
#pragma unroll
        for (int i = 0; i < 4; ++i) {
            int r = brow0 + i * 8 + lr;
            gload_lds16(Bm + (long)(n0 + r) * K + k0 + (lc ^ ((r & 7) << 3)), &Bs[r][lc]);
        }
        __syncthreads();
#pragma unroll
        for (int s = 0; s < 2; ++s) {
            bf16x8 af[4], bf[NN];
#pragma unroll
            for (int m = 0; m < 4; ++m) {
                int r = wro + m * 16 + fr;
                af[m] = *(const bf16x8*)((const char*)&As[r][0] + ((s * 64 + fo2) ^ ((r & 7) << 4)));
            }
#pragma unroll
            for (int n = 0; n < NN; ++n) {
                int r = wco + n * 16 + fr;
                bf[n] = *(const bf16x8*)((const char*)&Bs[r][0] + ((s * 64 + fo2) ^ ((r & 7) << 4)));
            }
            __builtin_amdgcn_s_setprio(1);
#pragma unroll
            for (int m = 0; m < 4; ++m)
#pragma unroll
                for (int n = 0; n < NN; ++n)
                    acc[m][n] = __builtin_amdgcn_mfma_f32_16x16x32_bf16(af[m], bf[n], acc[m][n], 0, 0, 0);
            __builtin_amdgcn_s_setprio(0);
        }
    }
    int fq = (lane >> 4) * 4;
#pragma unroll
    for (int m = 0; m < 4; ++m)
#pragma unroll
        for (int n = 0; n < NN; ++n) {
            int row = m0 + wro + m * 16 + fq;
            int col = n0 + wco + n * 16 + fr;
#pragma unroll
            for (int r = 0; r < 4; ++r) {
                float v = acc[m][n][r];
                long idx = (long)(row + r) * N + col;
                if (EPI == 1) {
                    if (bias) v += bias[col];
                    if (resid) v += resid[idx];
                    outF[idx] = v;
                } else {
                    int part = col >> 10, c = col & 1023;
                    __bf16* dst = (part == 0) ? qOut : (part == 1) ? kOut : vOut;
                    dst[(long)(row + r) * 1024 + c] = (__bf16)v;
                }
            }
        }
}

// ---------------- fused FFN1+FFN2: 128x128 dual-acc + T2 swizzle + XCD-chunk m-fast ----------------
__global__ __launch_bounds__(256, 2) void k_ffn(const __bf16* __restrict__ A,
                                                const __bf16* __restrict__ B1,
                                                const __bf16* __restrict__ B2,
                                                const float* __restrict__ b1,
                                                const float* __restrict__ b2,
                                                __bf16* __restrict__ outH) {
    __shared__ __align__(16) __bf16 As[128][64];
    __shared__ __align__(16) __bf16 B1s[128][64];
    __shared__ __align__(16) __bf16 B2s[128][64];
    int tid = threadIdx.x, lane = tid & 63, wave = tid >> 6;
    int nwg = 32 * (HIDP >> 7);          // 704
    int flat = blockIdx.x;
    int orig = (flat & 7) * (nwg >> 3) + (flat >> 3);
    int m0 = (orig & 31) * 128;          // m-fast (nm = 32)
    int n0 = (orig >> 5) * 128;
    int wro = (wave >> 1) * 64, wco = (wave & 1) * 64;
    int fr = lane & 15, fo2 = (lane >> 4) * 16;
    int sr = tid >> 3, sc = (tid & 7) * 8;
    f32x4 acc1[4][4] = {}, acc2[4][4] = {};
    for (int k0 = 0; k0 < Cv; k0 += 64) {
        __syncthreads();
#pragma unroll
        for (int i = 0; i < 4; ++i) {
            int r = i * 32 + sr;
            int scs = sc ^ ((r & 7) << 3);
            gload_lds16(A  + (long)(m0 + r) * Cv + k0 + scs, &As[r][sc]);
            gload_lds16(B1 + (long)(n0 + r) * Cv + k0 + scs, &B1s[r][sc]);
            gload_lds16(B2 + (long)(n0 + r) * Cv + k0 + scs, &B2s[r][sc]);
        }
        __syncthreads();
#pragma unroll
        for (int s = 0; s < 2; ++s) {
            bf16x8 af[4], b1f[4], b2f[4];
#pragma unroll
            for (int m = 0; m < 4; ++m) {
                int r = wro + m * 16 + fr;
                af[m] = *(const bf16x8*)((const char*)&As[r][0] + ((s * 64 + fo2) ^ ((r & 7) << 4)));
            }
#pragma unroll
            for (int n = 0; n < 4; ++n) {
                int r = wco + n * 16 + fr;
                b1f[n] = *(const bf16x8*)((const char*)&B1s[r][0] + ((s * 64 + fo2) ^ ((r & 7) << 4)));
                b2f[n] = *(const bf16x8*)((const char*)&B2s[r][0] + ((s * 64 + fo2) ^ ((r & 7) << 4)));
            }
            __builtin_amdgcn_s_setprio(1);
#pragma unroll
            for (int m = 0; m < 4; ++m)
#pragma unroll
                for (int n = 0; n < 4; ++n) {
                    acc1[m][n] = __builtin_amdgcn_mfma_f32_16x16x32_bf16(af[m], b1f[n], acc1[m][n], 0, 0, 0);
                    acc2[m][n] = __builtin_amdgcn_mfma_f32_16x16x32_bf16(af[m], b2f[n], acc2[m][n], 0, 0, 0);
                }
            __builtin_amdgcn_s_setprio(0);
        }
    }
    int fq = (lane >> 4) * 4;
#pragma unroll
    for (int m = 0; m < 4; ++m)
#pragma unroll
        for (int n = 0; n < 4; ++n) {
            int row = m0 + wro + m * 16 + fq;
            int col = n0 + wco + n * 16 + fr;
            float b1v = (col < HIDv) ? b1[col] : 0.0f;
            float b2v = (col < HIDv) ? b2[col] : 0.0f;
#pragma unroll
            for (int r = 0; r < 4; ++r) {
                float c1 = acc1[m][n][r] + b1v;
                float c2 = acc2[m][n][r] + b2v;
                float sw = c1 * (1.0f + __expf(-c1));
                outH[(long)(row + r) * HIDP + col] = (__bf16)(sw * c2);
            }
        }
}

// ---------------- flash attention (unchanged from round 7) ----------------
__global__ __launch_bounds__(256) void k_attn(const __bf16* __restrict__ Q,
                                              const __bf16* __restrict__ KR,
                                              const __bf16* __restrict__ VT,
                                              __bf16* __restrict__ O) {
    __shared__ __align__(16) __bf16 Ks[2][64][64];
    __shared__ __align__(16) __bf16 Vs[2][64][64];
    __shared__ __align__(16) __bf16 Ps[4][16][64];
    int tid = threadIdx.x, lane = tid & 63, w = tid >> 6;
    int bh = blockIdx.x >> 5;
    int qt = 31 - (blockIdx.x & 31);
    int q0 = qt * 64;
    int b = bh >> 4, h = bh & 15;
    const long qbase = ((long)b * Tv) * Cv + h * HSv;
    const long kbase = (long)bh * Tv * 64;
    const long vbase = (long)bh * 64 * Tv;
    int fr = lane & 15, g = lane >> 4;
    int go = g * 8;
    int lr = lane >> 3, lc8 = (lane & 7) * 8;
    int xr = (fr & 7) << 4;
    int qrow = q0 + w * 16 + fr;
    bf16x8 qf0 = *(const bf16x8*)(Q + qbase + (long)qrow * Cv + go);
    bf16x8 qf1 = *(const bf16x8*)(Q + qbase + (long)qrow * Cv + 32 + go);

    const float SCL = 0.125f * 1.44269504f;
    f32x4 o[4] = {};
    float mrow = -INFINITY, lrow = 0.0f;

    auto stage = [&](int j0, int bufi) {
#pragma unroll
        for (int i = 0; i < 2; ++i) {
            int rk = w * 16 + i * 8 + lr;
            gload_lds16(KR + kbase + (long)(j0 + rk) * 64 + lc8, &Ks[bufi][rk][lc8]);
            gload_lds16(VT + vbase + (long)rk * Tv + j0 + lc8, &Vs[bufi][rk][lc8]);
        }
    };

    stage(0, 0);
    for (int t = 0; t <= qt; ++t) {
        int cur = t & 1;
        __syncthreads();
        if (t < qt) stage((t + 1) * 64, cur ^ 1);
        f32x4 s4[4];
        __builtin_amdgcn_s_setprio(1);
#pragma unroll
        for (int kk = 0; kk < 4; ++kk) {
            int key = kk * 16 + fr;
            const char* krow = (const char*)&Ks[cur][key][0];
            bf16x8 kf0 = *(const bf16x8*)(krow + ((go * 2) ^ ((key & 7) << 4)));
            bf16x8 kf1 = *(const bf16x8*)(krow + ((64 + go * 2) ^ ((key & 7) << 4)));
            f32x4 z = {};
            z = __builtin_amdgcn_mfma_f32_16x16x32_bf16(kf0, qf0, z, 0, 0, 0);
            z = __builtin_amdgcn_mfma_f32_16x16x32_bf16(kf1, qf1, z, 0, 0, 0);
            s4[kk] = z;
        }
        __builtin_amdgcn_s_setprio(0);
        bool diag = (t == qt);
        if (diag) {
            int qloc = w * 16 + fr;
#pragma unroll
            for (int kk = 0; kk < 4; ++kk)
#pragma unroll
                for (int r = 0; r < 4; ++r) {
                    int key = kk * 16 + g * 4 + r;
                    s4[kk][r] = (key > qloc) ? -INFINITY : s4[kk][r] * SCL;
                }
        } else {
#pragma unroll
            for (int kk = 0; kk < 4; ++kk)
#pragma unroll
                for (int r = 0; r < 4; ++r) s4[kk][r] *= SCL;
        }
        float pmax = s4[0][0];
#pragma unroll
        for (int kk = 0; kk < 4; ++kk)
#pragma unroll
            for (int r = 0; r < 4; ++r) pmax = fmaxf(pmax, s4[kk][r]);
        pmax = fmaxf(pmax, __shfl_xor(pmax, 16));
        pmax = fmaxf(pmax, __shfl_xor(pmax, 32));
        bool keep = __all(pmax - mrow <= 8.0f);
        if (!keep) {
            float mn = fmaxf(mrow, pmax);
            float alpha = exp2f(mrow - mn);
            mrow = mn;
            lrow *= alpha;
#pragma unroll
            for (int fb = 0; fb < 4; ++fb)
#pragma unroll
                for (int r = 0; r < 4; ++r) o[fb][r] *= alpha;
        }
        float rs = 0.0f;
#pragma unroll
        for (int kk = 0; kk < 4; ++kk)
#pragma unroll
            for (int r = 0; r < 4; ++r) {
                float pv = exp2f(s4[kk][r] - mrow);
                s4[kk][r] = pv;
                rs += pv;
            }
        rs += __shfl_xor(rs, 16);
        rs += __shfl_xor(rs, 32);
        lrow += rs;
        char* prow = (char*)&Ps[w][fr][0];
#pragma unroll
        for (int kk = 0; kk < 4; ++kk) {
            __bf16 pk[4] = {(__bf16)s4[kk][0], (__bf16)s4[kk][1],
                            (__bf16)s4[kk][2], (__bf16)s4[kk][3]};
            *(ull*)(prow + ((kk * 32 + g * 8) ^ xr)) = *(ull*)pk;
        }
        const char* prd = prow;
        bf16x8 pa0 = *(const bf16x8*)(prd + ((g * 16) ^ xr));
        bf16x8 pa1 = *(const bf16x8*)(prd + ((64 + g * 16) ^ xr));
        __builtin_amdgcn_s_setprio(1);
#pragma unroll
        for (int fb = 0; fb < 4; ++fb) {
            int vrow = fb * 16 + fr;
            const char* vrd = (const char*)&Vs[cur][vrow][0];
            bf16x8 v0 = *(const bf16x8*)(vrd + ((go * 2) ^ ((vrow & 7) << 4)));
            bf16x8 v1 = *(const bf16x8*)(vrd + ((64 + go * 2) ^ ((vrow & 7) << 4)));
            o[fb] = __builtin_amdgcn_mfma_f32_16x16x32_bf16(v0, pa0, o[fb], 0, 0, 0);
            o[fb] = __builtin_amdgcn_mfma_f32_16x16x32_bf16(v1, pa1, o[fb], 0, 0, 0);
        }
        __builtin_amdgcn_s_setprio(0);
    }
    float rl = 1.0f / lrow;
#pragma unroll
    for (int fb = 0; fb < 4; ++fb) {
        __bf16 ov[4];
#pragma unroll
        for (int r = 0; r < 4; ++r) ov[r] = (__bf16)(o[fb][r] * rl);
        *(ull*)(O + qbase + (long)qrow * Cv + fb * 16 + g * 4) = *(ull*)ov;
    }
}

// ---------------- launch ----------------
extern "C" void kernel_launch(void* const* d_in, const int* in_sizes, int n_in,
                              void* d_out, int out_size, void* d_ws, size_t ws_size,
                              hipStream_t stream) {
    const float* x    = (const float*)d_in[0];
    const float* ln1w = (const float*)d_in[1];
    const float* Wq   = (const float*)d_in[2];
    const float* Wk   = (const float*)d_in[3];
    const float* Wv   = (const float*)d_in[4];
    const float* Wo   = (const float*)d_in[5];
    const float* bo   = (const float*)d_in[6];
    const float* w1   = (const float*)d_in[7];
    const float* b1   = (const float*)d_in[8];
    const float* w2   = (const float*)d_in[9];
    const float* b2   = (const float*)d_in[10];
    const float* w3   = (const float*)d_in[11];
    const float* b3   = (const float*)d_in[12];
    const float* ln2w = (const float*)d_in[13];
    const float* cosT = (const float*)d_in[14];
    const float* sinT = (const float*)d_in[15];
    float* out = (float*)d_out;

    char* p = (char*)d_ws;
    auto alloc = [&](size_t bytes) {
        char* r = p;
        p += (bytes + 255) & ~(size_t)255;
        return r;
    };
    float*  x1f = (float*)alloc((size_t)Mv * Cv * 4);
    __bf16* qh  = (__bf16*)alloc((size_t)Mv * Cv * 2);
    __bf16* kh  = (__bf16*)alloc((size_t)Mv * Cv * 2);
    __bf16* vh  = (__bf16*)alloc((size_t)Mv * Cv * 2);
    __bf16* ah  = (__bf16*)alloc((size_t)Mv * Cv * 2);
    float*  x3f = (float*)alloc((size_t)Mv * Cv * 4);
    __bf16* x1h = (__bf16*)alloc((size_t)Mv * Cv * 2);
    __bf16* VT  = (__bf16*)x1h;                                   // x1h dead after QKV GEMM
    __bf16* x3h = (__bf16*)alloc((size_t)Mv * Cv * 2);
    __bf16* KR  = (__bf16*)alloc((size_t)Bv * Hv * Tv * HSv * 2);
    __bf16* hh  = (__bf16*)alloc((size_t)Mv * HIDP * 2);
    __bf16* wqkvh = (__bf16*)alloc((size_t)3072 * Cv * 2);
    __bf16* woh = (__bf16*)alloc((size_t)Cv * Cv * 2);
    __bf16* w1h = (__bf16*)alloc((size_t)HIDP * Cv * 2);
    __bf16* w2h = (__bf16*)alloc((size_t)HIDP * Cv * 2);
    __bf16* w3h = (__bf16*)alloc((size_t)Cv * HIDP * 2);

    const long nCC = (long)Cv * Cv;
    CastArgs ca;
    ca.seg[0] = {Wq, wqkvh,           nCC, nCC, 0, 0};
    ca.seg[1] = {Wk, wqkvh + nCC,     nCC, nCC, 0, 0};
    ca.seg[2] = {Wv, wqkvh + 2 * nCC, nCC, nCC, 0, 0};
    ca.seg[3] = {Wo, woh,             nCC, nCC, 0, 0};
    ca.seg[4] = {w1, w1h, (long)HIDv * Cv, (long)HIDP * Cv, 0, 0};
    ca.seg[5] = {w2, w2h, (long)HIDv * Cv, (long)HIDP * Cv, 0, 0};
    ca.seg[6] = {w3, w3h, (long)Cv * HIDv, (long)Cv * HIDP, HIDv, HIDP};
    k_castall<<<2048, 256, 0, stream>>>(ca);

    k_rmsnorm<<<Mv, 256, 0, stream>>>(x, ln1w, x1f, x1h);

    // QKV: N = 3072, 768 blocks (1-D)
    k_gemm<128, 4><<<768, 256, 0, stream>>>(x1h, wqkvh, Mv, 3072, Cv,
        nullptr, nullptr, nullptr, qh, kh, vh);

    k_rope<<<(Mv * 512 + 255) / 256, 256, 0, stream>>>(qh, kh, KR, cosT, sinT);
    k_vtrans<<<dim3(Tv / 64, Bv * Hv), 256, 0, stream>>>(vh, VT);

    k_attn<<<1024, 256, 0, stream>>>(qh, KR, VT, ah);

    // x2 = x1 + attn @ Wo^T + bo  (into x1f), 512 blocks
    k_gemm<64, 1><<<512, 256, 0, stream>>>(ah, woh, Mv, Cv, Cv,
        x1f, bo, x1f, nullptr, nullptr, nullptr);

    k_rmsnorm<<<Mv, 256, 0, stream>>>(x1f, ln2w, x3f, x3h);

    // hh = swish_bug(x3@w1^T + b1) * (x3@w2^T + b2)  — 128x128 dual, 704 blocks
    k_ffn<<<704, 256, 0, stream>>>(x3h, w1h, w2h, b1, b2, hh);

    // out = x3 + hh @ w3^T + b3, 512 blocks
    k_gemm<64, 1><<<512, 256, 0, stream>>>(hh, w3h, Mv, Cv, HIDP,
        out, b3, x3f, nullptr, nullptr, nullptr);
}

// Round 9
// 291.953 us; speedup vs baseline: 1.2530x; 1.0273x over previous
//
#include <hip/hip_runtime.h>
#include <hip/hip_bf16.h>

#define Bv 2
#define Tv 2048
#define Cv 1024
#define Hv 16
#define HSv 64
#define HIDv 2730
#define HIDP 2816
#define Mv 4096

using bf16x8 = __attribute__((ext_vector_type(8))) __bf16;
using f32x4  = __attribute__((ext_vector_type(4))) float;
typedef unsigned long long ull;

__device__ __forceinline__ void gload_lds16(const void* g, void* l) {
    auto gp = (const __attribute__((address_space(1))) unsigned int*)(unsigned long long)(uintptr_t)g;
    auto lp = (__attribute__((address_space(3))) unsigned int*)(unsigned int)(uintptr_t)l;
    __builtin_amdgcn_global_load_lds(gp, lp, 16, 0, 0);
}

// ---------------- fused weight cast ----------------
struct CastSeg { const float* s; __bf16* d; long nsrc; long ntot; int sc; int dc; };
struct CastArgs { CastSeg seg[7]; };

__global__ __launch_bounds__(256) void k_castall(CastArgs a) {
    long gid = (long)blockIdx.x * 256 + threadIdx.x;
    long gstr = (long)gridDim.x * 256;
#pragma unroll 1
    for (int g = 0; g < 7; ++g) {
        CastSeg sg = a.seg[g];
        if (sg.sc == 0) {
            long n4 = sg.ntot >> 2;
            for (long i = gid; i < n4; i += gstr) {
                long base = i * 4;
                float4 v = {0.f, 0.f, 0.f, 0.f};
                if (base < sg.nsrc) v = *(const float4*)(sg.s + base);
                __bf16 o[4] = {(__bf16)v.x, (__bf16)v.y, (__bf16)v.z, (__bf16)v.w};
                *(ull*)(sg.d + base) = *(ull*)o;
            }
        } else {
            // pad-cols path, 8-wide (dc % 8 == 0 so groups never straddle rows)
            long n8 = sg.ntot >> 3;
            for (long i8 = gid; i8 < n8; i8 += gstr) {
                long base = i8 * 8;
                int r = (int)(base / sg.dc), c = (int)(base % sg.dc);
                __bf16 o[8];
                const float* srow = sg.s + (long)r * sg.sc + c;
                if (c + 8 <= sg.sc) {
#pragma unroll
                    for (int q = 0; q < 4; ++q) {
                        float2 v = *(const float2*)(srow + q * 2);
                        o[q * 2] = (__bf16)v.x; o[q * 2 + 1] = (__bf16)v.y;
                    }
                } else {
#pragma unroll
                    for (int e = 0; e < 8; ++e)
                        o[e] = (c + e < sg.sc) ? (__bf16)srow[e] : (__bf16)0.0f;
                }
                *(bf16x8*)(sg.d + base) = *(bf16x8*)o;
            }
        }
    }
}

// ---------------- rmsnorm ----------------
__global__ __launch_bounds__(256) void k_rmsnorm(const float* __restrict__ x,
                                                 const float* __restrict__ w,
                                                 float* __restrict__ yf,
                                                 __bf16* __restrict__ yh) {
    int row = blockIdx.x;
    const float4* xr = (const float4*)(x + (size_t)row * Cv);
    float4 a = xr[threadIdx.x];
    float ss = a.x * a.x + a.y * a.y + a.z * a.z + a.w * a.w;
#pragma unroll
    for (int m = 1; m < 64; m <<= 1) ss += __shfl_xor(ss, m);
    __shared__ float red[4];
    if ((threadIdx.x & 63) == 0) red[threadIdx.x >> 6] = ss;
    __syncthreads();
    float tot = red[0] + red[1] + red[2] + red[3];
    float sc = rsqrtf(tot * (1.0f / Cv) + 1e-6f);
    float4 wv = ((const float4*)w)[threadIdx.x];
    float4 o;
    o.x = a.x * sc * wv.x; o.y = a.y * sc * wv.y;
    o.z = a.z * sc * wv.z; o.w = a.w * sc * wv.w;
    ((float4*)(yf + (size_t)row * Cv))[threadIdx.x] = o;
    __bf16* yp = yh + (size_t)row * Cv + threadIdx.x * 4;
    yp[0] = (__bf16)o.x; yp[1] = (__bf16)o.y; yp[2] = (__bf16)o.z; yp[3] = (__bf16)o.w;
}

// ---------------- RoPE: Q in place; K -> KR[bh][t][64] pre-swizzled ----------------
__global__ void k_rope(__bf16* __restrict__ Q, const __bf16* __restrict__ Kin,
                       __bf16* __restrict__ KR,
                       const float* __restrict__ cosT, const float* __restrict__ sinT) {
    long total = (long)Mv * 512;
    long i = (long)blockIdx.x * blockDim.x + threadIdx.x;
    if (i >= total) return;
    int row = (int)(i >> 9);
    int p = (int)(i & 511);
    int h = p >> 5, ii = p & 31;
    int t = row & (Tv - 1), b = row >> 11;
    float c = cosT[t * 32 + ii], s = sinT[t * 32 + ii];
    long idx = (long)row * Cv + h * 64 + 2 * ii;
    float x0 = (float)Q[idx], x1 = (float)Q[idx + 1];
    Q[idx]     = (__bf16)(x0 * c - x1 * s);
    Q[idx + 1] = (__bf16)(x0 * s + x1 * c);
    float y0 = (float)Kin[idx], y1 = (float)Kin[idx + 1];
    __bf16 k0 = (__bf16)(y0 * c - y1 * s);
    __bf16 k1 = (__bf16)(y0 * s + y1 * c);
    int bh = b * 16 + h;
    int colb = (4 * ii) ^ ((t & 7) << 4);
    __bf16 pk[2] = {k0, k1};
    *(unsigned int*)((char*)(KR + ((long)bh * Tv + t) * 64) + colb) = *(unsigned int*)pk;
}

// ---------------- V transpose: VT[bh][f][t], pre-swizzled per 64-key tile ----------------
__global__ __launch_bounds__(256) void k_vtrans(const __bf16* __restrict__ V,
                                                __bf16* __restrict__ VT) {
    __shared__ __bf16 Ts[64][72];
    int t0 = blockIdx.x * 64;
    int bh = blockIdx.y, b = bh >> 4, h = bh & 15;
    const long base = ((long)b * Tv) * Cv + h * 64;
    int tid = threadIdx.x;
    int rr = tid >> 3, cc = (tid & 7) * 8;
#pragma unroll
    for (int it = 0; it < 2; ++it) {
        int row = it * 32 + rr;
        *(int4*)&Ts[row][cc] = *(const int4*)(V + base + (long)(t0 + row) * Cv + cc);
    }
    __syncthreads();
#pragma unroll
    for (int it = 0; it < 2; ++it) {
        int f = it * 32 + rr;
        int tcol = cc ^ ((f & 7) << 3);
        __bf16 tmp[8];
#pragma unroll
        for (int j = 0; j < 8; ++j) tmp[j] = Ts[tcol + j][f];
        *(int4*)(VT + ((long)bh * 64 + f) * Tv + t0 + cc) = *(int4*)tmp;
    }
}

// ---------------- GEMM (m97 structure + T2 source-XOR swizzle + XCD-chunk m-fast) ----------------
template <int BM, int EPI>
__global__ __launch_bounds__(256) void k_gemm(
    const __bf16* __restrict__ A, const __bf16* __restrict__ Bm,
    int M, int N, int K,
    float* __restrict__ outF,
    const float* __restrict__ bias,
    const float* __restrict__ resid,
    __bf16* __restrict__ qOut, __bf16* __restrict__ kOut, __bf16* __restrict__ vOut) {
    constexpr int NN = (BM == 128) ? 4 : 2;
    __shared__ __align__(16) __bf16 As[BM][64];
    __shared__ __align__(16) __bf16 Bs[128][64];
    int tid = threadIdx.x, lane = tid & 63, wave = tid >> 6;
    int nm = M / BM;
    int nwg = nm * (N >> 7);
    int flat = blockIdx.x;
    int orig = (flat & 7) * (nwg >> 3) + (flat >> 3);
    int m0 = (orig % nm) * BM;
    int n0 = (orig / nm) * 128;
    int wro = (BM == 128) ? (wave >> 1) * 64 : 0;
    int wco = (BM == 128) ? (wave & 1) * 64 : wave * 32;
    int fr = lane & 15, fo2 = (lane >> 4) * 16;
    int lr = lane >> 3, lc = (lane & 7) * 8;
    f32x4 acc[4][NN] = {};
    for (int k0 = 0; k0 < K; k0 += 64) {
        __syncthreads();
        int arow0 = wave * (BM / 4);
#pragma unroll
        for (int i = 0; i < BM / 32; ++i) {
            int r = arow0 + i * 8 + lr;
            gload_lds16(A + (long)(m0 + r) * K + k0 + (lc ^ ((r & 7) << 3)), &As[r][lc]);
        }
        int brow0 = wave * 32;
#pragma unroll
        for (int i = 0; i < 4; ++i) {
            int r = brow0 + i * 8 + lr;
            gload_lds16(Bm + (long)(n0 + r) * K + k0 + (lc ^ ((r & 7) << 3)), &Bs[r][lc]);
        }
        __syncthreads();
#pragma unroll
        for (int s = 0; s < 2; ++s) {
            bf16x8 af[4], bf[NN];
#pragma unroll
            for (int m = 0; m < 4; ++m) {
                int r = wro + m * 16 + fr;
                af[m] = *(const bf16x8*)((const char*)&As[r][0] + ((s * 64 + fo2) ^ ((r & 7) << 4)));
            }
#pragma unroll
            for (int n = 0; n < NN; ++n) {
                int r = wco + n * 16 + fr;
                bf[n] = *(const bf16x8*)((const char*)&Bs[r][0] + ((s * 64 + fo2) ^ ((r & 7) << 4)));
            }
            __builtin_amdgcn_s_setprio(1);
#pragma unroll
            for (int m = 0; m < 4; ++m)
#pragma unroll
                for (int n = 0; n < NN; ++n)
                    acc[m][n] = __builtin_amdgcn_mfma_f32_16x16x32_bf16(af[m], bf[n], acc[m][n], 0, 0, 0);
            __builtin_amdgcn_s_setprio(0);
        }
    }
    int fq = (lane >> 4) * 4;
#pragma unroll
    for (int m = 0; m < 4; ++m)
#pragma unroll
        for (int n = 0; n < NN; ++n) {
            int row = m0 + wro + m * 16 + fq;
            int col = n0 + wco + n * 16 + fr;
#pragma unroll
            for (int r = 0; r < 4; ++r) {
                float v = acc[m][n][r];
                long idx = (long)(row + r) * N + col;
                if (EPI == 1) {
                    if (bias) v += bias[col];
                    if (resid) v += resid[idx];
                    outF[idx] = v;
                } else {
                    int part = col >> 10, c = col & 1023;
                    __bf16* dst = (part == 0) ? qOut : (part == 1) ? kOut : vOut;
                    dst[(long)(row + r) * 1024 + c] = (__bf16)v;
                }
            }
        }
}

// ---------------- fused FFN1+FFN2: 128x128 dual-acc + T2 swizzle + XCD-chunk m-fast ----------------
__global__ __launch_bounds__(256, 2) void k_ffn(const __bf16* __restrict__ A,
                                                const __bf16* __restrict__ B1,
                                                const __bf16* __restrict__ B2,
                                                const float* __restrict__ b1,
                                                const float* __restrict__ b2,
                                                __bf16* __restrict__ outH) {
    __shared__ __align__(16) __bf16 As[128][64];
    __shared__ __align__(16) __bf16 B1s[128][64];
    __shared__ __align__(16) __bf16 B2s[128][64];
    int tid = threadIdx.x, lane = tid & 63, wave = tid >> 6;
    int nwg = 32 * (HIDP >> 7);
    int flat = blockIdx.x;
    int orig = (flat & 7) * (nwg >> 3) + (flat >> 3);
    int m0 = (orig & 31) * 128;
    int n0 = (orig >> 5) * 128;
    int wro = (wave >> 1) * 64, wco = (wave & 1) * 64;
    int fr = lane & 15, fo2 = (lane >> 4) * 16;
    int sr = tid >> 3, sc = (tid & 7) * 8;
    f32x4 acc1[4][4] = {}, acc2[4][4] = {};
    for (int k0 = 0; k0 < Cv; k0 += 64) {
        __syncthreads();
#pragma unroll
        for (int i = 0; i < 4; ++i) {
            int r = i * 32 + sr;
            int scs = sc ^ ((r & 7) << 3);
            gload_lds16(A  + (long)(m0 + r) * Cv + k0 + scs, &As[r][sc]);
            gload_lds16(B1 + (long)(n0 + r) * Cv + k0 + scs, &B1s[r][sc]);
            gload_lds16(B2 + (long)(n0 + r) * Cv + k0 + scs, &B2s[r][sc]);
        }
        __syncthreads();
#pragma unroll
        for (int s = 0; s < 2; ++s) {
            bf16x8 af[4], b1f[4], b2f[4];
#pragma unroll
            for (int m = 0; m < 4; ++m) {
                int r = wro + m * 16 + fr;
                af[m] = *(const bf16x8*)((const char*)&As[r][0] + ((s * 64 + fo2) ^ ((r & 7) << 4)));
            }
#pragma unroll
            for (int n = 0; n < 4; ++n) {
                int r = wco + n * 16 + fr;
                b1f[n] = *(const bf16x8*)((const char*)&B1s[r][0] + ((s * 64 + fo2) ^ ((r & 7) << 4)));
                b2f[n] = *(const bf16x8*)((const char*)&B2s[r][0] + ((s * 64 + fo2) ^ ((r & 7) << 4)));
            }
            __builtin_amdgcn_s_setprio(1);
#pragma unroll
            for (int m = 0; m < 4; ++m)
#pragma unroll
                for (int n = 0; n < 4; ++n) {
                    acc1[m][n] = __builtin_amdgcn_mfma_f32_16x16x32_bf16(af[m], b1f[n], acc1[m][n], 0, 0, 0);
                    acc2[m][n] = __builtin_amdgcn_mfma_f32_16x16x32_bf16(af[m], b2f[n], acc2[m][n], 0, 0, 0);
                }
            __builtin_amdgcn_s_setprio(0);
        }
    }
    int fq = (lane >> 4) * 4;
#pragma unroll
    for (int m = 0; m < 4; ++m)
#pragma unroll
        for (int n = 0; n < 4; ++n) {
            int row = m0 + wro + m * 16 + fq;
            int col = n0 + wco + n * 16 + fr;
            float b1v = (col < HIDv) ? b1[col] : 0.0f;
            float b2v = (col < HIDv) ? b2[col] : 0.0f;
#pragma unroll
            for (int r = 0; r < 4; ++r) {
                float c1 = acc1[m][n][r] + b1v;
                float c2 = acc2[m][n][r] + b2v;
                float sw = c1 * (1.0f + __expf(-c1));
                outH[(long)(row + r) * HIDP + col] = (__bf16)(sw * c2);
            }
        }
}

// ---------------- flash attention: QBLK=128, 2 q-frags/wave (ILP x2, shared K/V frags) ----------------
__global__ __launch_bounds__(256) void k_attn(const __bf16* __restrict__ Q,
                                              const __bf16* __restrict__ KR,
                                              const __bf16* __restrict__ VT,
                                              __bf16* __restrict__ O) {
    __shared__ __align__(16) __bf16 Ks[2][64][64];
    __shared__ __align__(16) __bf16 Vs[2][64][64];
    __shared__ __align__(16) __bf16 Ps[4][2][16][64];
    int tid = threadIdx.x, lane = tid & 63, w = tid >> 6;
    int bh = blockIdx.x & 31;                  // qt-major: heavy level first
    int qt = 15 - (blockIdx.x >> 5);
    int q0 = qt * 128;
    int b = bh >> 4, h = bh & 15;
    const long qbase = ((long)b * Tv) * Cv + h * HSv;
    const long kbase = (long)bh * Tv * 64;
    const long vbase = (long)bh * 64 * Tv;
    int fr = lane & 15, g = lane >> 4;
    int go = g * 8;
    int lr = lane >> 3, lc8 = (lane & 7) * 8;
    int xr = (fr & 7) << 4;
    int qrowA = q0 + w * 16 + fr;
    int qrowB = q0 + 64 + w * 16 + fr;
    bf16x8 qA0 = *(const bf16x8*)(Q + qbase + (long)qrowA * Cv + go);
    bf16x8 qA1 = *(const bf16x8*)(Q + qbase + (long)qrowA * Cv + 32 + go);
    bf16x8 qB0 = *(const bf16x8*)(Q + qbase + (long)qrowB * Cv + go);
    bf16x8 qB1 = *(const bf16x8*)(Q + qbase + (long)qrowB * Cv + 32 + go);

    const float SCL = 0.125f * 1.44269504f;
    f32x4 oA[4] = {}, oB[4] = {};
    float mA = -INFINITY, lA = 0.0f, mB = -INFINITY, lB = 0.0f;

    auto stage = [&](int j0, int bufi) {
#pragma unroll
        for (int i = 0; i < 2; ++i) {
            int rk = w * 16 + i * 8 + lr;
            gload_lds16(KR + kbase + (long)(j0 + rk) * 64 + lc8, &Ks[bufi][rk][lc8]);
            gload_lds16(VT + vbase + (long)rk * Tv + j0 + lc8, &Vs[bufi][rk][lc8]);
        }
    };

    int nt = 2 * qt + 2;                       // keys 0 .. q0+127
    stage(0, 0);
    for (int t = 0; t < nt; ++t) {
        int cur = t & 1;
        __syncthreads();
        if (t + 1 < nt) stage((t + 1) * 64, cur ^ 1);
        bool skipA = (t == nt - 1);            // fully masked for frag A
        bool diagA = (t == nt - 2);
        bool diagB = (t == nt - 1);
        // ---- QK^T: K frags shared between both q-frags ----
        f32x4 sA[4], sB[4];
        __builtin_amdgcn_s_setprio(1);
#pragma unroll
        for (int kk = 0; kk < 4; ++kk) {
            int key = kk * 16 + fr;
            const char* krow = (const char*)&Ks[cur][key][0];
            bf16x8 kf0 = *(const bf16x8*)(krow + ((go * 2) ^ ((key & 7) << 4)));
            bf16x8 kf1 = *(const bf16x8*)(krow + ((64 + go * 2) ^ ((key & 7) << 4)));
            f32x4 zB = {};
            zB = __builtin_amdgcn_mfma_f32_16x16x32_bf16(kf0, qB0, zB, 0, 0, 0);
            zB = __builtin_amdgcn_mfma_f32_16x16x32_bf16(kf1, qB1, zB, 0, 0, 0);
            sB[kk] = zB;
            if (!skipA) {
                f32x4 zA = {};
                zA = __builtin_amdgcn_mfma_f32_16x16x32_bf16(kf0, qA0, zA, 0, 0, 0);
                zA = __builtin_amdgcn_mfma_f32_16x16x32_bf16(kf1, qA1, zA, 0, 0, 0);
                sA[kk] = zA;
            }
        }
        __builtin_amdgcn_s_setprio(0);
        int qloc = w * 16 + fr;
        // ---- softmax frag A ----
        if (!skipA) {
            if (diagA) {
#pragma unroll
                for (int kk = 0; kk < 4; ++kk)
#pragma unroll
                    for (int r = 0; r < 4; ++r) {
                        int key = kk * 16 + g * 4 + r;
                        sA[kk][r] = (key > qloc) ? -INFINITY : sA[kk][r] * SCL;
                    }
            } else {
#pragma unroll
                for (int kk = 0; kk < 4; ++kk)
#pragma unroll
                    for (int r = 0; r < 4; ++r) sA[kk][r] *= SCL;
            }
            float pmax = sA[0][0];
#pragma unroll
            for (int kk = 0; kk < 4; ++kk)
#pragma unroll
                for (int r = 0; r < 4; ++r) pmax = fmaxf(pmax, sA[kk][r]);
            pmax = fmaxf(pmax, __shfl_xor(pmax, 16));
            pmax = fmaxf(pmax, __shfl_xor(pmax, 32));
            if (!__all(pmax - mA <= 8.0f)) {
                float mn = fmaxf(mA, pmax);
                float alpha = exp2f(mA - mn);
                mA = mn; lA *= alpha;
#pragma unroll
                for (int fb = 0; fb < 4; ++fb)
#pragma unroll
                    for (int r = 0; r < 4; ++r) oA[fb][r] *= alpha;
            }
            float rs = 0.0f;
#pragma unroll
            for (int kk = 0; kk < 4; ++kk)
#pragma unroll
                for (int r = 0; r < 4; ++r) {
                    float pv = exp2f(sA[kk][r] - mA);
                    sA[kk][r] = pv; rs += pv;
                }
            rs += __shfl_xor(rs, 16);
            rs += __shfl_xor(rs, 32);
            lA += rs;
            char* prow = (char*)&Ps[w][0][fr][0];
#pragma unroll
            for (int kk = 0; kk < 4; ++kk) {
                __bf16 pk[4] = {(__bf16)sA[kk][0], (__bf16)sA[kk][1],
                                (__bf16)sA[kk][2], (__bf16)sA[kk][3]};
                *(ull*)(prow + ((kk * 32 + g * 8) ^ xr)) = *(ull*)pk;
            }
        }
        // ---- softmax frag B ----
        {
            if (diagB) {
#pragma unroll
                for (int kk = 0; kk < 4; ++kk)
#pragma unroll
                    for (int r = 0; r < 4; ++r) {
                        int key = kk * 16 + g * 4 + r;
                        sB[kk][r] = (key > qloc) ? -INFINITY : sB[kk][r] * SCL;
                    }
            } else {
#pragma unroll
                for (int kk = 0; kk < 4; ++kk)
#pragma unroll
                    for (int r = 0; r < 4; ++r) sB[kk][r] *= SCL;
            }
            float pmax = sB[0][0];
#pragma unroll
            for (int kk = 0; kk < 4; ++kk)
#pragma unroll
                for (int r = 0; r < 4; ++r) pmax = fmaxf(pmax, sB[kk][r]);
            pmax = fmaxf(pmax, __shfl_xor(pmax, 16));
            pmax = fmaxf(pmax, __shfl_xor(pmax, 32));
            if (!__all(pmax - mB <= 8.0f)) {
                float mn = fmaxf(mB, pmax);
                float alpha = exp2f(mB - mn);
                mB = mn; lB *= alpha;
#pragma unroll
                for (int fb = 0; fb < 4; ++fb)
#pragma unroll
                    for (int r = 0; r < 4; ++r) oB[fb][r] *= alpha;
            }
            float rs = 0.0f;
#pragma unroll
            for (int kk = 0; kk < 4; ++kk)
#pragma unroll
                for (int r = 0; r < 4; ++r) {
                    float pv = exp2f(sB[kk][r] - mB);
                    sB[kk][r] = pv; rs += pv;
                }
            rs += __shfl_xor(rs, 16);
            rs += __shfl_xor(rs, 32);
            lB += rs;
            char* prow = (char*)&Ps[w][1][fr][0];
#pragma unroll
            for (int kk = 0; kk < 4; ++kk) {
                __bf16 pk[4] = {(__bf16)sB[kk][0], (__bf16)sB[kk][1],
                                (__bf16)sB[kk][2], (__bf16)sB[kk][3]};
                *(ull*)(prow + ((kk * 32 + g * 8) ^ xr)) = *(ull*)pk;
            }
        }
        // ---- PV: V frags shared between both q-frags ----
        const char* prA = (const char*)&Ps[w][0][fr][0];
        const char* prB = (const char*)&Ps[w][1][fr][0];
        bf16x8 paA0, paA1;
        if (!skipA) {
            paA0 = *(const bf16x8*)(prA + ((g * 16) ^ xr));
            paA1 = *(const bf16x8*)(prA + ((64 + g * 16) ^ xr));
        }
        bf16x8 paB0 = *(const bf16x8*)(prB + ((g * 16) ^ xr));
        bf16x8 paB1 = *(const bf16x8*)(prB + ((64 + g * 16) ^ xr));
        __builtin_amdgcn_s_setprio(1);
#pragma unroll
        for (int fb = 0; fb < 4; ++fb) {
            int vrow = fb * 16 + fr;
            const char* vrd = (const char*)&Vs[cur][vrow][0];
            bf16x8 v0 = *(const bf16x8*)(vrd + ((go * 2) ^ ((vrow & 7) << 4)));
            bf16x8 v1 = *(const bf16x8*)(vrd + ((64 + go * 2) ^ ((vrow & 7) << 4)));
            oB[fb] = __builtin_amdgcn_mfma_f32_16x16x32_bf16(v0, paB0, oB[fb], 0, 0, 0);
            oB[fb] = __builtin_amdgcn_mfma_f32_16x16x32_bf16(v1, paB1, oB[fb], 0, 0, 0);
            if (!skipA) {
                oA[fb] = __builtin_amdgcn_mfma_f32_16x16x32_bf16(v0, paA0, oA[fb], 0, 0, 0);
                oA[fb] = __builtin_amdgcn_mfma_f32_16x16x32_bf16(v1, paA1, oA[fb], 0, 0, 0);
            }
        }
        __builtin_amdgcn_s_setprio(0);
    }
    float rlA = 1.0f / lA, rlB = 1.0f / lB;
#pragma unroll
    for (int fb = 0; fb < 4; ++fb) {
        __bf16 ovA[4], ovB[4];
#pragma unroll
        for (int r = 0; r < 4; ++r) {
            ovA[r] = (__bf16)(oA[fb][r] * rlA);
            ovB[r] = (__bf16)(oB[fb][r] * rlB);
        }
        *(ull*)(O + qbase + (long)qrowA * Cv + fb * 16 + g * 4) = *(ull*)ovA;
        *(ull*)(O + qbase + (long)qrowB * Cv + fb * 16 + g * 4) = *(ull*)ovB;
    }
}

// ---------------- launch ----------------
extern "C" void kernel_launch(void* const* d_in, const int* in_sizes, int n_in,
                              void* d_out, int out_size, void* d_ws, size_t ws_size,
                              hipStream_t stream) {
    const float* x    = (const float*)d_in[0];
    const float* ln1w = (const float*)d_in[1];
    const float* Wq   = (const float*)d_in[2];
    const float* Wk   = (const float*)d_in[3];
    const float* Wv   = (const float*)d_in[4];
    const float* Wo   = (const float*)d_in[5];
    const float* bo   = (const float*)d_in[6];
    const float* w1   = (const float*)d_in[7];
    const float* b1   = (const float*)d_in[8];
    const float* w2   = (const float*)d_in[9];
    const float* b2   = (const float*)d_in[10];
    const float* w3   = (const float*)d_in[11];
    const float* b3   = (const float*)d_in[12];
    const float* ln2w = (const float*)d_in[13];
    const float* cosT = (const float*)d_in[14];
    const float* sinT = (const float*)d_in[15];
    float* out = (float*)d_out;

    char* p = (char*)d_ws;
    auto alloc = [&](size_t bytes) {
        char* r = p;
        p += (bytes + 255) & ~(size_t)255;
        return r;
    };
    float*  x1f = (float*)alloc((size_t)Mv * Cv * 4);
    __bf16* qh  = (__bf16*)alloc((size_t)Mv * Cv * 2);
    __bf16* kh  = (__bf16*)alloc((size_t)Mv * Cv * 2);
    __bf16* vh  = (__bf16*)alloc((size_t)Mv * Cv * 2);
    __bf16* ah  = (__bf16*)alloc((size_t)Mv * Cv * 2);
    float*  x3f = (float*)alloc((size_t)Mv * Cv * 4);
    __bf16* x1h = (__bf16*)alloc((size_t)Mv * Cv * 2);
    __bf16* VT  = (__bf16*)x1h;                                   // x1h dead after QKV GEMM
    __bf16* x3h = (__bf16*)alloc((size_t)Mv * Cv * 2);
    __bf16* KR  = (__bf16*)alloc((size_t)Bv * Hv * Tv * HSv * 2);
    __bf16* hh  = (__bf16*)alloc((size_t)Mv * HIDP * 2);
    __bf16* wqkvh = (__bf16*)alloc((size_t)3072 * Cv * 2);
    __bf16* woh = (__bf16*)alloc((size_t)Cv * Cv * 2);
    __bf16* w1h = (__bf16*)alloc((size_t)HIDP * Cv * 2);
    __bf16* w2h = (__bf16*)alloc((size_t)HIDP * Cv * 2);
    __bf16* w3h = (__bf16*)alloc((size_t)Cv * HIDP * 2);

    const long nCC = (long)Cv * Cv;
    CastArgs ca;
    ca.seg[0] = {Wq, wqkvh,           nCC, nCC, 0, 0};
    ca.seg[1] = {Wk, wqkvh + nCC,     nCC, nCC, 0, 0};
    ca.seg[2] = {Wv, wqkvh + 2 * nCC, nCC, nCC, 0, 0};
    ca.seg[3] = {Wo, woh,             nCC, nCC, 0, 0};
    ca.seg[4] = {w1, w1h, (long)HIDv * Cv, (long)HIDP * Cv, 0, 0};
    ca.seg[5] = {w2, w2h, (long)HIDv * Cv, (long)HIDP * Cv, 0, 0};
    ca.seg[6] = {w3, w3h, (long)Cv * HIDv, (long)Cv * HIDP, HIDv, HIDP};
    k_castall<<<2048, 256, 0, stream>>>(ca);

    k_rmsnorm<<<Mv, 256, 0, stream>>>(x, ln1w, x1f, x1h);

    // QKV: N = 3072, 768 blocks (1-D)
    k_gemm<128, 4><<<768, 256, 0, stream>>>(x1h, wqkvh, Mv, 3072, Cv,
        nullptr, nullptr, nullptr, qh, kh, vh);

    k_rope<<<(Mv * 512 + 255) / 256, 256, 0, stream>>>(qh, kh, KR, cosT, sinT);
    k_vtrans<<<dim3(Tv / 64, Bv * Hv), 256, 0, stream>>>(vh, VT);

    // attention: QBLK=128, 512 blocks
    k_attn<<<512, 256, 0, stream>>>(qh, KR, VT, ah);

    // x2 = x1 + attn @ Wo^T + bo  (into x1f), 512 blocks
    k_gemm<64, 1><<<512, 256, 0, stream>>>(ah, woh, Mv, Cv, Cv,
        x1f, bo, x1f, nullptr, nullptr, nullptr);

    k_rmsnorm<<<Mv, 256, 0, stream>>>(x1f, ln2w, x3f, x3h);

    // hh = swish_bug(x3@w1^T + b1) * (x3@w2^T + b2)  — 128x128 dual, 704 blocks
    k_ffn<<<704, 256, 0, stream>>>(x3h, w1h, w2h, b1, b2, hh);

    // out = x3 + hh @ w3^T + b3, 512 blocks
    k_gemm<64, 1><<<512, 256, 0, stream>>>(hh, w3h, Mv, Cv, HIDP,
        out, b3, x3f, nullptr, nullptr, nullptr);
}

// Round 10
// 289.857 us; speedup vs baseline: 1.2621x; 1.0072x over previous
//
#include <hip/hip_runtime.h>
#include <hip/hip_bf16.h>

#define Bv 2
#define Tv 2048
#define Cv 1024
#define Hv 16
#define HSv 64
#define HIDv 2730
#define HIDP 2816
#define Mv 4096

using bf16x8 = __attribute__((ext_vector_type(8))) __bf16;
using f32x4  = __attribute__((ext_vector_type(4))) float;
typedef unsigned long long ull;

__device__ __forceinline__ void gload_lds16(const void* g, void* l) {
    auto gp = (const __attribute__((address_space(1))) unsigned int*)(unsigned long long)(uintptr_t)g;
    auto lp = (__attribute__((address_space(3))) unsigned int*)(unsigned int)(uintptr_t)l;
    __builtin_amdgcn_global_load_lds(gp, lp, 16, 0, 0);
}

// ---------------- fused weight cast ----------------
struct CastSeg { const float* s; __bf16* d; long nsrc; long ntot; int sc; int dc; };
struct CastArgs { CastSeg seg[7]; };

__global__ __launch_bounds__(256) void k_castall(CastArgs a) {
    long gid = (long)blockIdx.x * 256 + threadIdx.x;
    long gstr = (long)gridDim.x * 256;
#pragma unroll 1
    for (int g = 0; g < 7; ++g) {
        CastSeg sg = a.seg[g];
        if (sg.sc == 0) {
            long n4 = sg.ntot >> 2;
            for (long i = gid; i < n4; i += gstr) {
                long base = i * 4;
                float4 v = {0.f, 0.f, 0.f, 0.f};
                if (base < sg.nsrc) v = *(const float4*)(sg.s + base);
                __bf16 o[4] = {(__bf16)v.x, (__bf16)v.y, (__bf16)v.z, (__bf16)v.w};
                *(ull*)(sg.d + base) = *(ull*)o;
            }
        } else {
            long n8 = sg.ntot >> 3;
            for (long i8 = gid; i8 < n8; i8 += gstr) {
                long base = i8 * 8;
                int r = (int)(base / sg.dc), c = (int)(base % sg.dc);
                __bf16 o[8];
                const float* srow = sg.s + (long)r * sg.sc + c;
                if (c + 8 <= sg.sc) {
#pragma unroll
                    for (int q = 0; q < 4; ++q) {
                        float2 v = *(const float2*)(srow + q * 2);
                        o[q * 2] = (__bf16)v.x; o[q * 2 + 1] = (__bf16)v.y;
                    }
                } else {
#pragma unroll
                    for (int e = 0; e < 8; ++e)
                        o[e] = (c + e < sg.sc) ? (__bf16)srow[e] : (__bf16)0.0f;
                }
                *(bf16x8*)(sg.d + base) = *(bf16x8*)o;
            }
        }
    }
}

// ---------------- rmsnorm ----------------
__global__ __launch_bounds__(256) void k_rmsnorm(const float* __restrict__ x,
                                                 const float* __restrict__ w,
                                                 float* __restrict__ yf,
                                                 __bf16* __restrict__ yh) {
    int row = blockIdx.x;
    const float4* xr = (const float4*)(x + (size_t)row * Cv);
    float4 a = xr[threadIdx.x];
    float ss = a.x * a.x + a.y * a.y + a.z * a.z + a.w * a.w;
#pragma unroll
    for (int m = 1; m < 64; m <<= 1) ss += __shfl_xor(ss, m);
    __shared__ float red[4];
    if ((threadIdx.x & 63) == 0) red[threadIdx.x >> 6] = ss;
    __syncthreads();
    float tot = red[0] + red[1] + red[2] + red[3];
    float sc = rsqrtf(tot * (1.0f / Cv) + 1e-6f);
    float4 wv = ((const float4*)w)[threadIdx.x];
    float4 o;
    o.x = a.x * sc * wv.x; o.y = a.y * sc * wv.y;
    o.z = a.z * sc * wv.z; o.w = a.w * sc * wv.w;
    ((float4*)(yf + (size_t)row * Cv))[threadIdx.x] = o;
    __bf16* yp = yh + (size_t)row * Cv + threadIdx.x * 4;
    yp[0] = (__bf16)o.x; yp[1] = (__bf16)o.y; yp[2] = (__bf16)o.z; yp[3] = (__bf16)o.w;
}

// ---------------- GEMM (m97 + T2 swizzle + XCD-chunk) ----------------
// EPI 1: outF = acc (+bias)(+resid)
// EPI 4: fused RoPE epilogue -> qOut (rope'd Q, row-major), kOut (KR pre-swizzled),
//        vOut (VT pre-swizzled transpose)
template <int BM, int EPI>
__global__ __launch_bounds__(256) void k_gemm(
    const __bf16* __restrict__ A, const __bf16* __restrict__ Bm,
    int M, int N, int K,
    float* __restrict__ outF,
    const float* __restrict__ bias,
    const float* __restrict__ resid,
    __bf16* __restrict__ qOut, __bf16* __restrict__ kOut, __bf16* __restrict__ vOut,
    const float* __restrict__ cosT, const float* __restrict__ sinT) {
    constexpr int NN = (BM == 128) ? 4 : 2;
    __shared__ __align__(16) __bf16 As[BM][64];
    __shared__ __align__(16) __bf16 Bs[128][64];
    int tid = threadIdx.x, lane = tid & 63, wave = tid >> 6;
    int nm = M / BM;
    int nwg = nm * (N >> 7);
    int flat = blockIdx.x;
    int orig = (flat & 7) * (nwg >> 3) + (flat >> 3);
    int m0 = (orig % nm) * BM;
    int n0 = (orig / nm) * 128;
    int wro = (BM == 128) ? (wave >> 1) * 64 : 0;
    int wco = (BM == 128) ? (wave & 1) * 64 : wave * 32;
    int fr = lane & 15, fo2 = (lane >> 4) * 16;
    int lr = lane >> 3, lc = (lane & 7) * 8;
    f32x4 acc[4][NN] = {};
    for (int k0 = 0; k0 < K; k0 += 64) {
        __syncthreads();
        int arow0 = wave * (BM / 4);
#pragma unroll
        for (int i = 0; i < BM / 32; ++i) {
            int r = arow0 + i * 8 + lr;
            gload_lds16(A + (long)(m0 + r) * K + k0 + (lc ^ ((r & 7) << 3)), &As[r][lc]);
        }
        int brow0 = wave * 32;
#pragma unroll
        for (int i = 0; i < 4; ++i) {
            int r = brow0 + i * 8 + lr;
            gload_lds16(Bm + (long)(n0 + r) * K + k0 + (lc ^ ((r & 7) << 3)), &Bs[r][lc]);
        }
        __syncthreads();
#pragma unroll
        for (int s = 0; s < 2; ++s) {
            bf16x8 af[4], bf[NN];
#pragma unroll
            for (int m = 0; m < 4; ++m) {
                int r = wro + m * 16 + fr;
                af[m] = *(const bf16x8*)((const char*)&As[r][0] + ((s * 64 + fo2) ^ ((r & 7) << 4)));
            }
#pragma unroll
            for (int n = 0; n < NN; ++n) {
                int r = wco + n * 16 + fr;
                bf[n] = *(const bf16x8*)((const char*)&Bs[r][0] + ((s * 64 + fo2) ^ ((r & 7) << 4)));
            }
            __builtin_amdgcn_s_setprio(1);
#pragma unroll
            for (int m = 0; m < 4; ++m)
#pragma unroll
                for (int n = 0; n < NN; ++n)
                    acc[m][n] = __builtin_amdgcn_mfma_f32_16x16x32_bf16(af[m], bf[n], acc[m][n], 0, 0, 0);
            __builtin_amdgcn_s_setprio(0);
        }
    }
    int fq = (lane >> 4) * 4;
    if (EPI == 1) {
#pragma unroll
        for (int m = 0; m < 4; ++m)
#pragma unroll
            for (int n = 0; n < NN; ++n) {
                int row = m0 + wro + m * 16 + fq;
                int col = n0 + wco + n * 16 + fr;
#pragma unroll
                for (int r = 0; r < 4; ++r) {
                    float v = acc[m][n][r];
                    long idx = (long)(row + r) * N + col;
                    if (bias) v += bias[col];
                    if (resid) v += resid[idx];
                    outF[idx] = v;
                }
            }
    } else {
        // fused RoPE (Q,K) + V-transpose epilogue
#pragma unroll
        for (int n = 0; n < NN; ++n) {
            int col = n0 + wco + n * 16 + fr;
            int part = col >> 10;          // wave-uniform (n-panel within one part)
            int cn = col & 1023;
            int hh = cn >> 6, d = cn & 63, ii = d >> 1;
            bool evn = (d & 1) == 0;
#pragma unroll
            for (int m = 0; m < 4; ++m) {
                int row = m0 + wro + m * 16 + fq;
                int bh = (row >> 11) * 16 + hh;
                int tb = row & (Tv - 1);
                if (part == 2) {
                    int X = (d & 7) << 3;
                    int tile0 = tb & ~63, toff = tb & 63;
                    __bf16 ov[4];
#pragma unroll
                    for (int r = 0; r < 4; ++r) ov[r] = (__bf16)acc[m][n][r];
                    *(ull*)(vOut + ((long)bh * 64 + d) * Tv + tile0 + (toff ^ X)) = *(ull*)ov;
                } else {
                    float pxv[4];
#pragma unroll
                    for (int r = 0; r < 4; ++r) pxv[r] = __shfl_xor(acc[m][n][r], 1);
                    if (evn) {
#pragma unroll
                        for (int r = 0; r < 4; ++r) {
                            int t = tb + r;
                            float c = cosT[t * 32 + ii], s = sinT[t * 32 + ii];
                            float x0 = acc[m][n][r], x1 = pxv[r];
                            __bf16 pr[2] = {(__bf16)(x0 * c - x1 * s),
                                            (__bf16)(x0 * s + x1 * c)};
                            if (part == 0) {
                                *(unsigned int*)(qOut + (long)(row + r) * 1024 + cn) = *(unsigned int*)pr;
                            } else {
                                char* base = (char*)(kOut + ((long)bh * Tv + t) * 64);
                                *(unsigned int*)(base + ((4 * ii) ^ ((t & 7) << 4))) = *(unsigned int*)pr;
                            }
                        }
                    }
                }
            }
        }
    }
}

// ---------------- fused FFN1+FFN2: 128x128 dual-acc + T2 swizzle + XCD-chunk ----------------
__global__ __launch_bounds__(256, 2) void k_ffn(const __bf16* __restrict__ A,
                                                const __bf16* __restrict__ B1,
                                                const __bf16* __restrict__ B2,
                                                const float* __restrict__ b1,
                                                const float* __restrict__ b2,
                                                __bf16* __restrict__ outH) {
    __shared__ __align__(16) __bf16 As[128][64];
    __shared__ __align__(16) __bf16 B1s[128][64];
    __shared__ __align__(16) __bf16 B2s[128][64];
    int tid = threadIdx.x, lane = tid & 63, wave = tid >> 6;
    int nwg = 32 * (HIDP >> 7);
    int flat = blockIdx.x;
    int orig = (flat & 7) * (nwg >> 3) + (flat >> 3);
    int m0 = (orig & 31) * 128;
    int n0 = (orig >> 5) * 128;
    int wro = (wave >> 1) * 64, wco = (wave & 1) * 64;
    int fr = lane & 15, fo2 = (lane >> 4) * 16;
    int sr = tid >> 3, sc = (tid & 7) * 8;
    f32x4 acc1[4][4] = {}, acc2[4][4] = {};
    for (int k0 = 0; k0 < Cv; k0 += 64) {
        __syncthreads();
#pragma unroll
        for (int i = 0; i < 4; ++i) {
            int r = i * 32 + sr;
            int scs = sc ^ ((r & 7) << 3);
            gload_lds16(A  + (long)(m0 + r) * Cv + k0 + scs, &As[r][sc]);
            gload_lds16(B1 + (long)(n0 + r) * Cv + k0 + scs, &B1s[r][sc]);
            gload_lds16(B2 + (long)(n0 + r) * Cv + k0 + scs, &B2s[r][sc]);
        }
        __syncthreads();
#pragma unroll
        for (int s = 0; s < 2; ++s) {
            bf16x8 af[4], b1f[4], b2f[4];
#pragma unroll
            for (int m = 0; m < 4; ++m) {
                int r = wro + m * 16 + fr;
                af[m] = *(const bf16x8*)((const char*)&As[r][0] + ((s * 64 + fo2) ^ ((r & 7) << 4)));
            }
#pragma unroll
            for (int n = 0; n < 4; ++n) {
                int r = wco + n * 16 + fr;
                b1f[n] = *(const bf16x8*)((const char*)&B1s[r][0] + ((s * 64 + fo2) ^ ((r & 7) << 4)));
                b2f[n] = *(const bf16x8*)((const char*)&B2s[r][0] + ((s * 64 + fo2) ^ ((r & 7) << 4)));
            }
            __builtin_amdgcn_s_setprio(1);
#pragma unroll
            for (int m = 0; m < 4; ++m)
#pragma unroll
                for (int n = 0; n < 4; ++n) {
                    acc1[m][n] = __builtin_amdgcn_mfma_f32_16x16x32_bf16(af[m], b1f[n], acc1[m][n], 0, 0, 0);
                    acc2[m][n] = __builtin_amdgcn_mfma_f32_16x16x32_bf16(af[m], b2f[n], acc2[m][n], 0, 0, 0);
                }
            __builtin_amdgcn_s_setprio(0);
        }
    }
    int fq = (lane >> 4) * 4;
#pragma unroll
    for (int m = 0; m < 4; ++m)
#pragma unroll
        for (int n = 0; n < 4; ++n) {
            int row = m0 + wro + m * 16 + fq;
            int col = n0 + wco + n * 16 + fr;
            float b1v = (col < HIDv) ? b1[col] : 0.0f;
            float b2v = (col < HIDv) ? b2[col] : 0.0f;
#pragma unroll
            for (int r = 0; r < 4; ++r) {
                float c1 = acc1[m][n][r] + b1v;
                float c2 = acc2[m][n][r] + b2v;
                float sw = c1 * (1.0f + __expf(-c1));
                outH[(long)(row + r) * HIDP + col] = (__bf16)(sw * c2);
            }
        }
}

// ---------------- flash attention: QBLK=128, 2 q-frags/wave, MFMA l-sum ----------------
__global__ __launch_bounds__(256) void k_attn(const __bf16* __restrict__ Q,
                                              const __bf16* __restrict__ KR,
                                              const __bf16* __restrict__ VT,
                                              __bf16* __restrict__ O) {
    __shared__ __align__(16) __bf16 Ks[2][64][64];
    __shared__ __align__(16) __bf16 Vs[2][64][64];
    __shared__ __align__(16) __bf16 Ps[4][2][16][64];
    int tid = threadIdx.x, lane = tid & 63, w = tid >> 6;
    int bh = blockIdx.x & 31;
    int qt = 15 - (blockIdx.x >> 5);
    int q0 = qt * 128;
    int b = bh >> 4, h = bh & 15;
    const long qbase = ((long)b * Tv) * Cv + h * HSv;
    const long kbase = (long)bh * Tv * 64;
    const long vbase = (long)bh * 64 * Tv;
    int fr = lane & 15, g = lane >> 4;
    int go = g * 8;
    int lr = lane >> 3, lc8 = (lane & 7) * 8;
    int xr = (fr & 7) << 4;
    int qrowA = q0 + w * 16 + fr;
    int qrowB = q0 + 64 + w * 16 + fr;
    bf16x8 qA0 = *(const bf16x8*)(Q + qbase + (long)qrowA * Cv + go);
    bf16x8 qA1 = *(const bf16x8*)(Q + qbase + (long)qrowA * Cv + 32 + go);
    bf16x8 qB0 = *(const bf16x8*)(Q + qbase + (long)qrowB * Cv + go);
    bf16x8 qB1 = *(const bf16x8*)(Q + qbase + (long)qrowB * Cv + 32 + go);

    bf16x8 ones;
#pragma unroll
    for (int e = 0; e < 8; ++e) ones[e] = (__bf16)1.0f;

    const float SCL = 0.125f * 1.44269504f;
    f32x4 oA[4] = {}, oB[4] = {};
    f32x4 lsA = {}, lsB = {};
    float mA = -INFINITY, mB = -INFINITY;

    auto stage = [&](int j0, int bufi) {
#pragma unroll
        for (int i = 0; i < 2; ++i) {
            int rk = w * 16 + i * 8 + lr;
            gload_lds16(KR + kbase + (long)(j0 + rk) * 64 + lc8, &Ks[bufi][rk][lc8]);
            gload_lds16(VT + vbase + (long)rk * Tv + j0 + lc8, &Vs[bufi][rk][lc8]);
        }
    };

    int nt = 2 * qt + 2;
    stage(0, 0);
    for (int t = 0; t < nt; ++t) {
        int cur = t & 1;
        __syncthreads();
        if (t + 1 < nt) stage((t + 1) * 64, cur ^ 1);
        bool skipA = (t == nt - 1);
        bool diagA = (t == nt - 2);
        bool diagB = (t == nt - 1);
        f32x4 sA[4], sB[4];
        __builtin_amdgcn_s_setprio(1);
#pragma unroll
        for (int kk = 0; kk < 4; ++kk) {
            int key = kk * 16 + fr;
            const char* krow = (const char*)&Ks[cur][key][0];
            bf16x8 kf0 = *(const bf16x8*)(krow + ((go * 2) ^ ((key & 7) << 4)));
            bf16x8 kf1 = *(const bf16x8*)(krow + ((64 + go * 2) ^ ((key & 7) << 4)));
            f32x4 zB = {};
            zB = __builtin_amdgcn_mfma_f32_16x16x32_bf16(kf0, qB0, zB, 0, 0, 0);
            zB = __builtin_amdgcn_mfma_f32_16x16x32_bf16(kf1, qB1, zB, 0, 0, 0);
            sB[kk] = zB;
            if (!skipA) {
                f32x4 zA = {};
                zA = __builtin_amdgcn_mfma_f32_16x16x32_bf16(kf0, qA0, zA, 0, 0, 0);
                zA = __builtin_amdgcn_mfma_f32_16x16x32_bf16(kf1, qA1, zA, 0, 0, 0);
                sA[kk] = zA;
            }
        }
        __builtin_amdgcn_s_setprio(0);
        int qloc = w * 16 + fr;
        // ---- softmax frag A ----
        if (!skipA) {
            if (diagA) {
#pragma unroll
                for (int kk = 0; kk < 4; ++kk)
#pragma unroll
                    for (int r = 0; r < 4; ++r) {
                        int key = kk * 16 + g * 4 + r;
                        sA[kk][r] = (key > qloc) ? -INFINITY : sA[kk][r] * SCL;
                    }
            } else {
#pragma unroll
                for (int kk = 0; kk < 4; ++kk)
#pragma unroll
                    for (int r = 0; r < 4; ++r) sA[kk][r] *= SCL;
            }
            float pmax = sA[0][0];
#pragma unroll
            for (int kk = 0; kk < 4; ++kk)
#pragma unroll
                for (int r = 0; r < 4; ++r) pmax = fmaxf(pmax, sA[kk][r]);
            pmax = fmaxf(pmax, __shfl_xor(pmax, 16));
            pmax = fmaxf(pmax, __shfl_xor(pmax, 32));
            if (!__all(pmax - mA <= 8.0f)) {
                float mn = fmaxf(mA, pmax);
                float alpha = exp2f(mA - mn);
                mA = mn;
#pragma unroll
                for (int r = 0; r < 4; ++r) lsA[r] *= alpha;
#pragma unroll
                for (int fb = 0; fb < 4; ++fb)
#pragma unroll
                    for (int r = 0; r < 4; ++r) oA[fb][r] *= alpha;
            }
            char* prow = (char*)&Ps[w][0][fr][0];
#pragma unroll
            for (int kk = 0; kk < 4; ++kk) {
                __bf16 pk[4];
#pragma unroll
                for (int r = 0; r < 4; ++r) pk[r] = (__bf16)exp2f(sA[kk][r] - mA);
                *(ull*)(prow + ((kk * 32 + g * 8) ^ xr)) = *(ull*)pk;
            }
        }
        // ---- softmax frag B ----
        {
            if (diagB) {
#pragma unroll
                for (int kk = 0; kk < 4; ++kk)
#pragma unroll
                    for (int r = 0; r < 4; ++r) {
                        int key = kk * 16 + g * 4 + r;
                        sB[kk][r] = (key > qloc) ? -INFINITY : sB[kk][r] * SCL;
                    }
            } else {
#pragma unroll
                for (int kk = 0; kk < 4; ++kk)
#pragma unroll
                    for (int r = 0; r < 4; ++r) sB[kk][r] *= SCL;
            }
            float pmax = sB[0][0];
#pragma unroll
            for (int kk = 0; kk < 4; ++kk)
#pragma unroll
                for (int r = 0; r < 4; ++r) pmax = fmaxf(pmax, sB[kk][r]);
            pmax = fmaxf(pmax, __shfl_xor(pmax, 16));
            pmax = fmaxf(pmax, __shfl_xor(pmax, 32));
            if (!__all(pmax - mB <= 8.0f)) {
                float mn = fmaxf(mB, pmax);
                float alpha = exp2f(mB - mn);
                mB = mn;
#pragma unroll
                for (int r = 0; r < 4; ++r) lsB[r] *= alpha;
#pragma unroll
                for (int fb = 0; fb < 4; ++fb)
#pragma unroll
                    for (int r = 0; r < 4; ++r) oB[fb][r] *= alpha;
            }
            char* prow = (char*)&Ps[w][1][fr][0];
#pragma unroll
            for (int kk = 0; kk < 4; ++kk) {
                __bf16 pk[4];
#pragma unroll
                for (int r = 0; r < 4; ++r) pk[r] = (__bf16)exp2f(sB[kk][r] - mB);
                *(ull*)(prow + ((kk * 32 + g * 8) ^ xr)) = *(ull*)pk;
            }
        }
        // ---- PV + MFMA l-sum (V frags shared) ----
        const char* prA = (const char*)&Ps[w][0][fr][0];
        const char* prB = (const char*)&Ps[w][1][fr][0];
        bf16x8 paA0, paA1;
        if (!skipA) {
            paA0 = *(const bf16x8*)(prA + ((g * 16) ^ xr));
            paA1 = *(const bf16x8*)(prA + ((64 + g * 16) ^ xr));
        }
        bf16x8 paB0 = *(const bf16x8*)(prB + ((g * 16) ^ xr));
        bf16x8 paB1 = *(const bf16x8*)(prB + ((64 + g * 16) ^ xr));
        __builtin_amdgcn_s_setprio(1);
        if (!skipA) {
            lsA = __builtin_amdgcn_mfma_f32_16x16x32_bf16(ones, paA0, lsA, 0, 0, 0);
            lsA = __builtin_amdgcn_mfma_f32_16x16x32_bf16(ones, paA1, lsA, 0, 0, 0);
        }
        lsB = __builtin_amdgcn_mfma_f32_16x16x32_bf16(ones, paB0, lsB, 0, 0, 0);
        lsB = __builtin_amdgcn_mfma_f32_16x16x32_bf16(ones, paB1, lsB, 0, 0, 0);
#pragma unroll
        for (int fb = 0; fb < 4; ++fb) {
            int vrow = fb * 16 + fr;
            const char* vrd = (const char*)&Vs[cur][vrow][0];
            bf16x8 v0 = *(const bf16x8*)(vrd + ((go * 2) ^ ((vrow & 7) << 4)));
            bf16x8 v1 = *(const bf16x8*)(vrd + ((64 + go * 2) ^ ((vrow & 7) << 4)));
            oB[fb] = __builtin_amdgcn_mfma_f32_16x16x32_bf16(v0, paB0, oB[fb], 0, 0, 0);
            oB[fb] = __builtin_amdgcn_mfma_f32_16x16x32_bf16(v1, paB1, oB[fb], 0, 0, 0);
            if (!skipA) {
                oA[fb] = __builtin_amdgcn_mfma_f32_16x16x32_bf16(v0, paA0, oA[fb], 0, 0, 0);
                oA[fb] = __builtin_amdgcn_mfma_f32_16x16x32_bf16(v1, paA1, oA[fb], 0, 0, 0);
            }
        }
        __builtin_amdgcn_s_setprio(0);
    }
    float rlA = 1.0f / lsA[0], rlB = 1.0f / lsB[0];
#pragma unroll
    for (int fb = 0; fb < 4; ++fb) {
        __bf16 ovA[4], ovB[4];
#pragma unroll
        for (int r = 0; r < 4; ++r) {
            ovA[r] = (__bf16)(oA[fb][r] * rlA);
            ovB[r] = (__bf16)(oB[fb][r] * rlB);
        }
        *(ull*)(O + qbase + (long)qrowA * Cv + fb * 16 + g * 4) = *(ull*)ovA;
        *(ull*)(O + qbase + (long)qrowB * Cv + fb * 16 + g * 4) = *(ull*)ovB;
    }
}

// ---------------- launch ----------------
extern "C" void kernel_launch(void* const* d_in, const int* in_sizes, int n_in,
                              void* d_out, int out_size, void* d_ws, size_t ws_size,
                              hipStream_t stream) {
    const float* x    = (const float*)d_in[0];
    const float* ln1w = (const float*)d_in[1];
    const float* Wq   = (const float*)d_in[2];
    const float* Wk   = (const float*)d_in[3];
    const float* Wv   = (const float*)d_in[4];
    const float* Wo   = (const float*)d_in[5];
    const float* bo   = (const float*)d_in[6];
    const float* w1   = (const float*)d_in[7];
    const float* b1   = (const float*)d_in[8];
    const float* w2   = (const float*)d_in[9];
    const float* b2   = (const float*)d_in[10];
    const float* w3   = (const float*)d_in[11];
    const float* b3   = (const float*)d_in[12];
    const float* ln2w = (const float*)d_in[13];
    const float* cosT = (const float*)d_in[14];
    const float* sinT = (const float*)d_in[15];
    float* out = (float*)d_out;

    char* p = (char*)d_ws;
    auto alloc = [&](size_t bytes) {
        char* r = p;
        p += (bytes + 255) & ~(size_t)255;
        return r;
    };
    float*  x1f = (float*)alloc((size_t)Mv * Cv * 4);
    __bf16* qh  = (__bf16*)alloc((size_t)Mv * Cv * 2);
    __bf16* ah  = (__bf16*)alloc((size_t)Mv * Cv * 2);
    float*  x3f = (float*)alloc((size_t)Mv * Cv * 4);
    __bf16* x1h = (__bf16*)alloc((size_t)Mv * Cv * 2);
    __bf16* x3h = (__bf16*)alloc((size_t)Mv * Cv * 2);
    __bf16* KR  = (__bf16*)alloc((size_t)Bv * Hv * Tv * HSv * 2);   // 8 MB
    __bf16* VT  = (__bf16*)alloc((size_t)Bv * Hv * HSv * Tv * 2);   // 8 MB (own buffer!)
    __bf16* hh  = (__bf16*)alloc((size_t)Mv * HIDP * 2);
    __bf16* wqkvh = (__bf16*)alloc((size_t)3072 * Cv * 2);
    __bf16* woh = (__bf16*)alloc((size_t)Cv * Cv * 2);
    __bf16* w1h = (__bf16*)alloc((size_t)HIDP * Cv * 2);
    __bf16* w2h = (__bf16*)alloc((size_t)HIDP * Cv * 2);
    __bf16* w3h = (__bf16*)alloc((size_t)Cv * HIDP * 2);

    const long nCC = (long)Cv * Cv;
    CastArgs ca;
    ca.seg[0] = {Wq, wqkvh,           nCC, nCC, 0, 0};
    ca.seg[1] = {Wk, wqkvh + nCC,     nCC, nCC, 0, 0};
    ca.seg[2] = {Wv, wqkvh + 2 * nCC, nCC, nCC, 0, 0};
    ca.seg[3] = {Wo, woh,             nCC, nCC, 0, 0};
    ca.seg[4] = {w1, w1h, (long)HIDv * Cv, (long)HIDP * Cv, 0, 0};
    ca.seg[5] = {w2, w2h, (long)HIDv * Cv, (long)HIDP * Cv, 0, 0};
    ca.seg[6] = {w3, w3h, (long)Cv * HIDv, (long)Cv * HIDP, HIDv, HIDP};
    k_castall<<<2048, 256, 0, stream>>>(ca);

    k_rmsnorm<<<Mv, 256, 0, stream>>>(x, ln1w, x1f, x1h);

    // QKV GEMM with fused RoPE + V-transpose epilogue (replaces rope + vtrans kernels)
    k_gemm<128, 4><<<768, 256, 0, stream>>>(x1h, wqkvh, Mv, 3072, Cv,
        nullptr, nullptr, nullptr, qh, KR, VT, cosT, sinT);

    k_attn<<<512, 256, 0, stream>>>(qh, KR, VT, ah);

    // x2 = x1 + attn @ Wo^T + bo  (into x1f)
    k_gemm<64, 1><<<512, 256, 0, stream>>>(ah, woh, Mv, Cv, Cv,
        x1f, bo, x1f, nullptr, nullptr, nullptr, nullptr, nullptr);

    k_rmsnorm<<<Mv, 256, 0, stream>>>(x1f, ln2w, x3f, x3h);

    k_ffn<<<704, 256, 0, stream>>>(x3h, w1h, w2h, b1, b2, hh);

    // out = x3 + hh @ w3^T + b3
    k_gemm<64, 1><<<512, 256, 0, stream>>>(hh, w3h, Mv, Cv, HIDP,
        out, b3, x3f, nullptr, nullptr, nullptr, nullptr, nullptr);
}

// Round 11
// 272.212 us; speedup vs baseline: 1.3439x; 1.0648x over previous
//
#include <hip/hip_runtime.h>
#include <hip/hip_bf16.h>

#define Bv 2
#define Tv 2048
#define Cv 1024
#define Hv 16
#define HSv 64
#define HIDv 2730
#define HIDP 2816
#define Mv 4096

using bf16x8 = __attribute__((ext_vector_type(8))) __bf16;
using f32x4  = __attribute__((ext_vector_type(4))) float;
typedef unsigned long long ull;

__device__ __forceinline__ void gload_lds16(const void* g, void* l) {
    auto gp = (const __attribute__((address_space(1))) unsigned int*)(unsigned long long)(uintptr_t)g;
    auto lp = (__attribute__((address_space(3))) unsigned int*)(unsigned int)(uintptr_t)l;
    __builtin_amdgcn_global_load_lds(gp, lp, 16, 0, 0);
}

// ---------------- fused weight cast ----------------
struct CastSeg { const float* s; __bf16* d; long nsrc; long ntot; int sc; int dc; };
struct CastArgs { CastSeg seg[7]; };

__global__ __launch_bounds__(256) void k_castall(CastArgs a) {
    long gid = (long)blockIdx.x * 256 + threadIdx.x;
    long gstr = (long)gridDim.x * 256;
#pragma unroll 1
    for (int g = 0; g < 7; ++g) {
        CastSeg sg = a.seg[g];
        if (sg.sc == 0) {
            long n4 = sg.ntot >> 2;
            for (long i = gid; i < n4; i += gstr) {
                long base = i * 4;
                float4 v = {0.f, 0.f, 0.f, 0.f};
                if (base < sg.nsrc) v = *(const float4*)(sg.s + base);
                __bf16 o[4] = {(__bf16)v.x, (__bf16)v.y, (__bf16)v.z, (__bf16)v.w};
                *(ull*)(sg.d + base) = *(ull*)o;
            }
        } else {
            long n8 = sg.ntot >> 3;
            for (long i8 = gid; i8 < n8; i8 += gstr) {
                long base = i8 * 8;
                int r = (int)(base / sg.dc), c = (int)(base % sg.dc);
                __bf16 o[8];
                const float* srow = sg.s + (long)r * sg.sc + c;
                if (c + 8 <= sg.sc) {
#pragma unroll
                    for (int q = 0; q < 4; ++q) {
                        float2 v = *(const float2*)(srow + q * 2);
                        o[q * 2] = (__bf16)v.x; o[q * 2 + 1] = (__bf16)v.y;
                    }
                } else {
#pragma unroll
                    for (int e = 0; e < 8; ++e)
                        o[e] = (c + e < sg.sc) ? (__bf16)srow[e] : (__bf16)0.0f;
                }
                *(bf16x8*)(sg.d + base) = *(bf16x8*)o;
            }
        }
    }
}

// ---------------- rmsnorm ----------------
__global__ __launch_bounds__(256) void k_rmsnorm(const float* __restrict__ x,
                                                 const float* __restrict__ w,
                                                 float* __restrict__ yf,
                                                 __bf16* __restrict__ yh) {
    int row = blockIdx.x;
    const float4* xr = (const float4*)(x + (size_t)row * Cv);
    float4 a = xr[threadIdx.x];
    float ss = a.x * a.x + a.y * a.y + a.z * a.z + a.w * a.w;
#pragma unroll
    for (int m = 1; m < 64; m <<= 1) ss += __shfl_xor(ss, m);
    __shared__ float red[4];
    if ((threadIdx.x & 63) == 0) red[threadIdx.x >> 6] = ss;
    __syncthreads();
    float tot = red[0] + red[1] + red[2] + red[3];
    float sc = rsqrtf(tot * (1.0f / Cv) + 1e-6f);
    float4 wv = ((const float4*)w)[threadIdx.x];
    float4 o;
    o.x = a.x * sc * wv.x; o.y = a.y * sc * wv.y;
    o.z = a.z * sc * wv.z; o.w = a.w * sc * wv.w;
    ((float4*)(yf + (size_t)row * Cv))[threadIdx.x] = o;
    __bf16* yp = yh + (size_t)row * Cv + threadIdx.x * 4;
    yp[0] = (__bf16)o.x; yp[1] = (__bf16)o.y; yp[2] = (__bf16)o.z; yp[3] = (__bf16)o.w;
}

// ---------------- GEMM (m97 + T2 swizzle + XCD-chunk) ----------------
// EPI 1: outF = acc (+bias)(+resid)
// EPI 4: fused RoPE epilogue -> qOut (rope'd + SCL-prescaled Q), kOut (KR pre-swizzled),
//        vOut (VT pre-swizzled transpose)
template <int BM, int EPI>
__global__ __launch_bounds__(256) void k_gemm(
    const __bf16* __restrict__ A, const __bf16* __restrict__ Bm,
    int M, int N, int K,
    float* __restrict__ outF,
    const float* __restrict__ bias,
    const float* __restrict__ resid,
    __bf16* __restrict__ qOut, __bf16* __restrict__ kOut, __bf16* __restrict__ vOut,
    const float* __restrict__ cosT, const float* __restrict__ sinT) {
    constexpr int NN = (BM == 128) ? 4 : 2;
    __shared__ __align__(16) __bf16 As[BM][64];
    __shared__ __align__(16) __bf16 Bs[128][64];
    int tid = threadIdx.x, lane = tid & 63, wave = tid >> 6;
    int nm = M / BM;
    int nwg = nm * (N >> 7);
    int flat = blockIdx.x;
    int orig = (flat & 7) * (nwg >> 3) + (flat >> 3);
    int m0 = (orig % nm) * BM;
    int n0 = (orig / nm) * 128;
    int wro = (BM == 128) ? (wave >> 1) * 64 : 0;
    int wco = (BM == 128) ? (wave & 1) * 64 : wave * 32;
    int fr = lane & 15, fo2 = (lane >> 4) * 16;
    int lr = lane >> 3, lc = (lane & 7) * 8;
    f32x4 acc[4][NN] = {};
    for (int k0 = 0; k0 < K; k0 += 64) {
        __syncthreads();
        int arow0 = wave * (BM / 4);
#pragma unroll
        for (int i = 0; i < BM / 32; ++i) {
            int r = arow0 + i * 8 + lr;
            gload_lds16(A + (long)(m0 + r) * K + k0 + (lc ^ ((r & 7) << 3)), &As[r][lc]);
        }
        int brow0 = wave * 32;
#pragma unroll
        for (int i = 0; i < 4; ++i) {
            int r = brow0 + i * 8 + lr;
            gload_lds16(Bm + (long)(n0 + r) * K + k0 + (lc ^ ((r & 7) << 3)), &Bs[r][lc]);
        }
        __syncthreads();
#pragma unroll
        for (int s = 0; s < 2; ++s) {
            bf16x8 af[4], bf[NN];
#pragma unroll
            for (int m = 0; m < 4; ++m) {
                int r = wro + m * 16 + fr;
                af[m] = *(const bf16x8*)((const char*)&As[r][0] + ((s * 64 + fo2) ^ ((r & 7) << 4)));
            }
#pragma unroll
            for (int n = 0; n < NN; ++n) {
                int r = wco + n * 16 + fr;
                bf[n] = *(const bf16x8*)((const char*)&Bs[r][0] + ((s * 64 + fo2) ^ ((r & 7) << 4)));
            }
            __builtin_amdgcn_s_setprio(1);
#pragma unroll
            for (int m = 0; m < 4; ++m)
#pragma unroll
                for (int n = 0; n < NN; ++n)
                    acc[m][n] = __builtin_amdgcn_mfma_f32_16x16x32_bf16(af[m], bf[n], acc[m][n], 0, 0, 0);
            __builtin_amdgcn_s_setprio(0);
        }
    }
    int fq = (lane >> 4) * 4;
    if (EPI == 1) {
#pragma unroll
        for (int m = 0; m < 4; ++m)
#pragma unroll
            for (int n = 0; n < NN; ++n) {
                int row = m0 + wro + m * 16 + fq;
                int col = n0 + wco + n * 16 + fr;
#pragma unroll
                for (int r = 0; r < 4; ++r) {
                    float v = acc[m][n][r];
                    long idx = (long)(row + r) * N + col;
                    if (bias) v += bias[col];
                    if (resid) v += resid[idx];
                    outF[idx] = v;
                }
            }
    } else {
        const float SCL = 0.125f * 1.44269504f;
#pragma unroll
        for (int n = 0; n < NN; ++n) {
            int col = n0 + wco + n * 16 + fr;
            int part = col >> 10;
            int cn = col & 1023;
            int hh = cn >> 6, d = cn & 63, ii = d >> 1;
            bool evn = (d & 1) == 0;
#pragma unroll
            for (int m = 0; m < 4; ++m) {
                int row = m0 + wro + m * 16 + fq;
                int bh = (row >> 11) * 16 + hh;
                int tb = row & (Tv - 1);
                if (part == 2) {
                    int X = (d & 7) << 3;
                    int tile0 = tb & ~63, toff = tb & 63;
                    __bf16 ov[4];
#pragma unroll
                    for (int r = 0; r < 4; ++r) ov[r] = (__bf16)acc[m][n][r];
                    *(ull*)(vOut + ((long)bh * 64 + d) * Tv + tile0 + (toff ^ X)) = *(ull*)ov;
                } else {
                    float pxv[4];
#pragma unroll
                    for (int r = 0; r < 4; ++r) pxv[r] = __shfl_xor(acc[m][n][r], 1);
                    if (evn) {
#pragma unroll
                        for (int r = 0; r < 4; ++r) {
                            int t = tb + r;
                            float c = cosT[t * 32 + ii], s = sinT[t * 32 + ii];
                            float x0 = acc[m][n][r], x1 = pxv[r];
                            float r0 = x0 * c - x1 * s;
                            float r1 = x0 * s + x1 * c;
                            if (part == 0) {
                                __bf16 pr[2] = {(__bf16)(r0 * SCL), (__bf16)(r1 * SCL)};
                                *(unsigned int*)(qOut + (long)(row + r) * 1024 + cn) = *(unsigned int*)pr;
                            } else {
                                __bf16 pr[2] = {(__bf16)r0, (__bf16)r1};
                                char* base = (char*)(kOut + ((long)bh * Tv + t) * 64);
                                *(unsigned int*)(base + ((4 * ii) ^ ((t & 7) << 4))) = *(unsigned int*)pr;
                            }
                        }
                    }
                }
            }
        }
    }
}

// ---------------- fused FFN1+FFN2: 128x128 dual-acc + T2 swizzle + XCD-chunk ----------------
__global__ __launch_bounds__(256, 2) void k_ffn(const __bf16* __restrict__ A,
                                                const __bf16* __restrict__ B1,
                                                const __bf16* __restrict__ B2,
                                                const float* __restrict__ b1,
                                                const float* __restrict__ b2,
                                                __bf16* __restrict__ outH) {
    __shared__ __align__(16) __bf16 As[128][64];
    __shared__ __align__(16) __bf16 B1s[128][64];
    __shared__ __align__(16) __bf16 B2s[128][64];
    int tid = threadIdx.x, lane = tid & 63, wave = tid >> 6;
    int nwg = 32 * (HIDP >> 7);
    int flat = blockIdx.x;
    int orig = (flat & 7) * (nwg >> 3) + (flat >> 3);
    int m0 = (orig & 31) * 128;
    int n0 = (orig >> 5) * 128;
    int wro = (wave >> 1) * 64, wco = (wave & 1) * 64;
    int fr = lane & 15, fo2 = (lane >> 4) * 16;
    int sr = tid >> 3, sc = (tid & 7) * 8;
    f32x4 acc1[4][4] = {}, acc2[4][4] = {};
    for (int k0 = 0; k0 < Cv; k0 += 64) {
        __syncthreads();
#pragma unroll
        for (int i = 0; i < 4; ++i) {
            int r = i * 32 + sr;
            int scs = sc ^ ((r & 7) << 3);
            gload_lds16(A  + (long)(m0 + r) * Cv + k0 + scs, &As[r][sc]);
            gload_lds16(B1 + (long)(n0 + r) * Cv + k0 + scs, &B1s[r][sc]);
            gload_lds16(B2 + (long)(n0 + r) * Cv + k0 + scs, &B2s[r][sc]);
        }
        __syncthreads();
#pragma unroll
        for (int s = 0; s < 2; ++s) {
            bf16x8 af[4], b1f[4], b2f[4];
#pragma unroll
            for (int m = 0; m < 4; ++m) {
                int r = wro + m * 16 + fr;
                af[m] = *(const bf16x8*)((const char*)&As[r][0] + ((s * 64 + fo2) ^ ((r & 7) << 4)));
            }
#pragma unroll
            for (int n = 0; n < 4; ++n) {
                int r = wco + n * 16 + fr;
                b1f[n] = *(const bf16x8*)((const char*)&B1s[r][0] + ((s * 64 + fo2) ^ ((r & 7) << 4)));
                b2f[n] = *(const bf16x8*)((const char*)&B2s[r][0] + ((s * 64 + fo2) ^ ((r & 7) << 4)));
            }
            __builtin_amdgcn_s_setprio(1);
#pragma unroll
            for (int m = 0; m < 4; ++m)
#pragma unroll
                for (int n = 0; n < 4; ++n) {
                    acc1[m][n] = __builtin_amdgcn_mfma_f32_16x16x32_bf16(af[m], b1f[n], acc1[m][n], 0, 0, 0);
                    acc2[m][n] = __builtin_amdgcn_mfma_f32_16x16x32_bf16(af[m], b2f[n], acc2[m][n], 0, 0, 0);
                }
            __builtin_amdgcn_s_setprio(0);
        }
    }
    int fq = (lane >> 4) * 4;
#pragma unroll
    for (int m = 0; m < 4; ++m)
#pragma unroll
        for (int n = 0; n < 4; ++n) {
            int row = m0 + wro + m * 16 + fq;
            int col = n0 + wco + n * 16 + fr;
            float b1v = (col < HIDv) ? b1[col] : 0.0f;
            float b2v = (col < HIDv) ? b2[col] : 0.0f;
#pragma unroll
            for (int r = 0; r < 4; ++r) {
                float c1 = acc1[m][n][r] + b1v;
                float c2 = acc2[m][n][r] + b2v;
                float sw = c1 * (1.0f + __expf(-c1));
                outH[(long)(row + r) * HIDP + col] = (__bf16)(sw * c2);
            }
        }
}

// ---------------- flash attention: QBLK=128, KBLK=128, 2 q-frags, PV half-passes ----------------
__global__ __launch_bounds__(256) void k_attn(const __bf16* __restrict__ Q,
                                              const __bf16* __restrict__ KR,
                                              const __bf16* __restrict__ VT,
                                              __bf16* __restrict__ O) {
    __shared__ __align__(16) __bf16 Ks[2][128][64];   // 32 KB
    __shared__ __align__(16) __bf16 Vs[2][64][128];   // 32 KB
    __shared__ __align__(16) __bf16 Ps[4][2][16][64]; // 16 KB
    int tid = threadIdx.x, lane = tid & 63, w = tid >> 6;
    int bh = blockIdx.x & 31;
    int qt = 15 - (blockIdx.x >> 5);
    int q0 = qt * 128;
    int b = bh >> 4, h = bh & 15;
    const long qbase = ((long)b * Tv) * Cv + h * HSv;
    const long kbase = (long)bh * Tv * 64;
    const long vbase = (long)bh * 64 * Tv;
    int fr = lane & 15, g = lane >> 4;
    int go = g * 8;
    int xr = (fr & 7) << 4;
    int qrowA = q0 + w * 16 + fr;
    int qrowB = q0 + 64 + w * 16 + fr;
    bf16x8 qA0 = *(const bf16x8*)(Q + qbase + (long)qrowA * Cv + go);
    bf16x8 qA1 = *(const bf16x8*)(Q + qbase + (long)qrowA * Cv + 32 + go);
    bf16x8 qB0 = *(const bf16x8*)(Q + qbase + (long)qrowB * Cv + go);
    bf16x8 qB1 = *(const bf16x8*)(Q + qbase + (long)qrowB * Cv + 32 + go);

    bf16x8 ones;
#pragma unroll
    for (int e = 0; e < 8; ++e) ones[e] = (__bf16)1.0f;

    f32x4 oA[4] = {}, oB[4] = {};
    f32x4 lsA = {}, lsB = {};
    float mA = -INFINITY, mB = -INFINITY;

    // stage 128 keys: K [128][64] + V [64][128], both linear lane*16B dests
    auto stage = [&](int j0, int bufi) {
#pragma unroll
        for (int i = 0; i < 4; ++i) {
            int rk = i * 32 + w * 8 + (lane >> 3);
            gload_lds16(KR + kbase + (long)(j0 + rk) * 64 + (lane & 7) * 8,
                        &Ks[bufi][rk][(lane & 7) * 8]);
        }
#pragma unroll
        for (int i = 0; i < 4; ++i) {
            int rv = w * 16 + i * 4 + (lane >> 4);
            gload_lds16(VT + vbase + (long)rv * Tv + j0 + (lane & 15) * 8,
                        &Vs[bufi][rv][(lane & 15) * 8]);
        }
    };

    stage(0, 0);
    for (int t = 0; t <= qt; ++t) {
        int cur = t & 1;
        __syncthreads();
        if (t < qt) stage((t + 1) * 128, cur ^ 1);
        bool diag = (t == qt);
        f32x4 sA[8], sB[8];
        __builtin_amdgcn_s_setprio(1);
#pragma unroll
        for (int kk = 0; kk < 8; ++kk) {
            int key = kk * 16 + fr;
            const char* krow = (const char*)&Ks[cur][key][0];
            bf16x8 kf0 = *(const bf16x8*)(krow + ((go * 2) ^ ((key & 7) << 4)));
            bf16x8 kf1 = *(const bf16x8*)(krow + ((64 + go * 2) ^ ((key & 7) << 4)));
            f32x4 zB = {};
            zB = __builtin_amdgcn_mfma_f32_16x16x32_bf16(kf0, qB0, zB, 0, 0, 0);
            zB = __builtin_amdgcn_mfma_f32_16x16x32_bf16(kf1, qB1, zB, 0, 0, 0);
            sB[kk] = zB;
            if (!(diag && kk >= 4)) {
                f32x4 zA = {};
                zA = __builtin_amdgcn_mfma_f32_16x16x32_bf16(kf0, qA0, zA, 0, 0, 0);
                zA = __builtin_amdgcn_mfma_f32_16x16x32_bf16(kf1, qA1, zA, 0, 0, 0);
                sA[kk] = zA;
            } else {
                f32x4 ninf = {-INFINITY, -INFINITY, -INFINITY, -INFINITY};
                sA[kk] = ninf;
            }
        }
        __builtin_amdgcn_s_setprio(0);
        // causal mask (Q pre-scaled; no scale mult needed)
        if (diag) {
            int qlA = w * 16 + fr;       // A diag in subtiles 0..3
            int qlB = 64 + w * 16 + fr;  // B diag in subtiles 4..7
#pragma unroll
            for (int kk = 0; kk < 4; ++kk)
#pragma unroll
                for (int r = 0; r < 4; ++r) {
                    int key = kk * 16 + g * 4 + r;
                    if (key > qlA) sA[kk][r] = -INFINITY;
                }
#pragma unroll
            for (int kk = 4; kk < 8; ++kk)
#pragma unroll
                for (int r = 0; r < 4; ++r) {
                    int key = kk * 16 + g * 4 + r;
                    if (key > qlB) sB[kk][r] = -INFINITY;
                }
        }
        // pmax (both frags, independent chains)
        float pmA = sA[0][0], pmB = sB[0][0];
#pragma unroll
        for (int kk = 0; kk < 8; ++kk)
#pragma unroll
            for (int r = 0; r < 4; ++r) {
                pmA = fmaxf(pmA, sA[kk][r]);
                pmB = fmaxf(pmB, sB[kk][r]);
            }
        pmA = fmaxf(pmA, __shfl_xor(pmA, 16));
        pmA = fmaxf(pmA, __shfl_xor(pmA, 32));
        pmB = fmaxf(pmB, __shfl_xor(pmB, 16));
        pmB = fmaxf(pmB, __shfl_xor(pmB, 32));
        if (!__all(pmA - mA <= 8.0f)) {
            float mn = fmaxf(mA, pmA);
            float alpha = exp2f(mA - mn);
            mA = mn;
#pragma unroll
            for (int r = 0; r < 4; ++r) lsA[r] *= alpha;
#pragma unroll
            for (int fb = 0; fb < 4; ++fb)
#pragma unroll
                for (int r = 0; r < 4; ++r) oA[fb][r] *= alpha;
        }
        if (!__all(pmB - mB <= 8.0f)) {
            float mn = fmaxf(mB, pmB);
            float alpha = exp2f(mB - mn);
            mB = mn;
#pragma unroll
            for (int r = 0; r < 4; ++r) lsB[r] *= alpha;
#pragma unroll
            for (int fb = 0; fb < 4; ++fb)
#pragma unroll
                for (int r = 0; r < 4; ++r) oB[fb][r] *= alpha;
        }
        // two PV half-passes over shared Ps tiles
        char* prA = (char*)&Ps[w][0][fr][0];
        char* prB = (char*)&Ps[w][1][fr][0];
#pragma unroll
        for (int hf = 0; hf < 2; ++hf) {
            bool actA = !(diag && hf == 1);
            if (actA) {
#pragma unroll
                for (int kk = 0; kk < 4; ++kk) {
                    int ks = hf * 4 + kk;
                    __bf16 pk[4];
#pragma unroll
                    for (int r = 0; r < 4; ++r) pk[r] = (__bf16)exp2f(sA[ks][r] - mA);
                    *(ull*)(prA + ((kk * 32 + g * 8) ^ xr)) = *(ull*)pk;
                }
            }
#pragma unroll
            for (int kk = 0; kk < 4; ++kk) {
                int ks = hf * 4 + kk;
                __bf16 pk[4];
#pragma unroll
                for (int r = 0; r < 4; ++r) pk[r] = (__bf16)exp2f(sB[ks][r] - mB);
                *(ull*)(prB + ((kk * 32 + g * 8) ^ xr)) = *(ull*)pk;
            }
            bf16x8 paA0, paA1;
            if (actA) {
                paA0 = *(const bf16x8*)(prA + ((g * 16) ^ xr));
                paA1 = *(const bf16x8*)(prA + ((64 + g * 16) ^ xr));
            }
            bf16x8 paB0 = *(const bf16x8*)(prB + ((g * 16) ^ xr));
            bf16x8 paB1 = *(const bf16x8*)(prB + ((64 + g * 16) ^ xr));
            __builtin_amdgcn_s_setprio(1);
            if (actA) {
                lsA = __builtin_amdgcn_mfma_f32_16x16x32_bf16(ones, paA0, lsA, 0, 0, 0);
                lsA = __builtin_amdgcn_mfma_f32_16x16x32_bf16(ones, paA1, lsA, 0, 0, 0);
            }
            lsB = __builtin_amdgcn_mfma_f32_16x16x32_bf16(ones, paB0, lsB, 0, 0, 0);
            lsB = __builtin_amdgcn_mfma_f32_16x16x32_bf16(ones, paB1, lsB, 0, 0, 0);
#pragma unroll
            for (int fb = 0; fb < 4; ++fb) {
                int vrow = fb * 16 + fr;
                const char* vrd = (const char*)&Vs[cur][vrow][0];
                bf16x8 v0 = *(const bf16x8*)(vrd + hf * 128 + ((go * 2) ^ ((vrow & 7) << 4)));
                bf16x8 v1 = *(const bf16x8*)(vrd + hf * 128 + ((64 + go * 2) ^ ((vrow & 7) << 4)));
                oB[fb] = __builtin_amdgcn_mfma_f32_16x16x32_bf16(v0, paB0, oB[fb], 0, 0, 0);
                oB[fb] = __builtin_amdgcn_mfma_f32_16x16x32_bf16(v1, paB1, oB[fb], 0, 0, 0);
                if (actA) {
                    oA[fb] = __builtin_amdgcn_mfma_f32_16x16x32_bf16(v0, paA0, oA[fb], 0, 0, 0);
                    oA[fb] = __builtin_amdgcn_mfma_f32_16x16x32_bf16(v1, paA1, oA[fb], 0, 0, 0);
                }
            }
            __builtin_amdgcn_s_setprio(0);
        }
    }
    float rlA = 1.0f / lsA[0], rlB = 1.0f / lsB[0];
#pragma unroll
    for (int fb = 0; fb < 4; ++fb) {
        __bf16 ovA[4], ovB[4];
#pragma unroll
        for (int r = 0; r < 4; ++r) {
            ovA[r] = (__bf16)(oA[fb][r] * rlA);
            ovB[r] = (__bf16)(oB[fb][r] * rlB);
        }
        *(ull*)(O + qbase + (long)qrowA * Cv + fb * 16 + g * 4) = *(ull*)ovA;
        *(ull*)(O + qbase + (long)qrowB * Cv + fb * 16 + g * 4) = *(ull*)ovB;
    }
}

// ---------------- launch ----------------
extern "C" void kernel_launch(void* const* d_in, const int* in_sizes, int n_in,
                              void* d_out, int out_size, void* d_ws, size_t ws_size,
                              hipStream_t stream) {
    const float* x    = (const float*)d_in[0];
    const float* ln1w = (const float*)d_in[1];
    const float* Wq   = (const float*)d_in[2];
    const float* Wk   = (const float*)d_in[3];
    const float* Wv   = (const float*)d_in[4];
    const float* Wo   = (const float*)d_in[5];
    const float* bo   = (const float*)d_in[6];
    const float* w1   = (const float*)d_in[7];
    const float* b1   = (const float*)d_in[8];
    const float* w2   = (const float*)d_in[9];
    const float* b2   = (const float*)d_in[10];
    const float* w3   = (const float*)d_in[11];
    const float* b3   = (const float*)d_in[12];
    const float* ln2w = (const float*)d_in[13];
    const float* cosT = (const float*)d_in[14];
    const float* sinT = (const float*)d_in[15];
    float* out = (float*)d_out;

    char* p = (char*)d_ws;
    auto alloc = [&](size_t bytes) {
        char* r = p;
        p += (bytes + 255) & ~(size_t)255;
        return r;
    };
    float*  x1f = (float*)alloc((size_t)Mv * Cv * 4);
    __bf16* qh  = (__bf16*)alloc((size_t)Mv * Cv * 2);
    __bf16* ah  = (__bf16*)alloc((size_t)Mv * Cv * 2);
    float*  x3f = (float*)alloc((size_t)Mv * Cv * 4);
    __bf16* x1h = (__bf16*)alloc((size_t)Mv * Cv * 2);
    __bf16* x3h = (__bf16*)alloc((size_t)Mv * Cv * 2);
    __bf16* KR  = (__bf16*)alloc((size_t)Bv * Hv * Tv * HSv * 2);
    __bf16* VT  = (__bf16*)alloc((size_t)Bv * Hv * HSv * Tv * 2);
    __bf16* hh  = (__bf16*)alloc((size_t)Mv * HIDP * 2);
    __bf16* wqkvh = (__bf16*)alloc((size_t)3072 * Cv * 2);
    __bf16* woh = (__bf16*)alloc((size_t)Cv * Cv * 2);
    __bf16* w1h = (__bf16*)alloc((size_t)HIDP * Cv * 2);
    __bf16* w2h = (__bf16*)alloc((size_t)HIDP * Cv * 2);
    __bf16* w3h = (__bf16*)alloc((size_t)Cv * HIDP * 2);

    const long nCC = (long)Cv * Cv;
    CastArgs ca;
    ca.seg[0] = {Wq, wqkvh,           nCC, nCC, 0, 0};
    ca.seg[1] = {Wk, wqkvh + nCC,     nCC, nCC, 0, 0};
    ca.seg[2] = {Wv, wqkvh + 2 * nCC, nCC, nCC, 0, 0};
    ca.seg[3] = {Wo, woh,             nCC, nCC, 0, 0};
    ca.seg[4] = {w1, w1h, (long)HIDv * Cv, (long)HIDP * Cv, 0, 0};
    ca.seg[5] = {w2, w2h, (long)HIDv * Cv, (long)HIDP * Cv, 0, 0};
    ca.seg[6] = {w3, w3h, (long)Cv * HIDv, (long)Cv * HIDP, HIDv, HIDP};
    k_castall<<<2048, 256, 0, stream>>>(ca);

    k_rmsnorm<<<Mv, 256, 0, stream>>>(x, ln1w, x1f, x1h);

    // QKV GEMM with fused RoPE(+Q prescale) + V-transpose epilogue
    k_gemm<128, 4><<<768, 256, 0, stream>>>(x1h, wqkvh, Mv, 3072, Cv,
        nullptr, nullptr, nullptr, qh, KR, VT, cosT, sinT);

    k_attn<<<512, 256, 0, stream>>>(qh, KR, VT, ah);

    // x2 = x1 + attn @ Wo^T + bo  (into x1f)
    k_gemm<64, 1><<<512, 256, 0, stream>>>(ah, woh, Mv, Cv, Cv,
        x1f, bo, x1f, nullptr, nullptr, nullptr, nullptr, nullptr);

    k_rmsnorm<<<Mv, 256, 0, stream>>>(x1f, ln2w, x3f, x3h);

    k_ffn<<<704, 256, 0, stream>>>(x3h, w1h, w2h, b1, b2, hh);

    // out = x3 + hh @ w3^T + b3
    k_gemm<64, 1><<<512, 256, 0, stream>>>(hh, w3h, Mv, Cv, HIDP,
        out, b3, x3f, nullptr, nullptr, nullptr, nullptr, nullptr);
}